// Round 11
// baseline (4603.636 us; speedup 1.0000x reference)
//
#include <hip/hip_runtime.h>
#include <stdint.h>

// ---------------------------------------------------------------------------
// QuantumOlfactoryReceptor: full pipeline
// Round 11: k_rec -> k_layer: COLUMN-SPLIT LSTM recurrence.
//  256 WGs = 16 sample-groups x 16 col-groups. Each WG holds its 64-row
//  Whh slice in REGISTERS for the whole launch (no per-step weight stream --
//  the invariant that defeated 8 rounds of sample-split k_rec experiments).
//  h exchanged via global ping-pong + device-scope software grid barrier
//  (release add / relaxed spin / acquire; 256 WGs <= 256 CUs co-resident;
//  counter memset per launch -> graph-replay deterministic).
// ---------------------------------------------------------------------------

using short8 = __attribute__((ext_vector_type(8))) short;
using f32x4  = __attribute__((ext_vector_type(4))) float;

#define DEV static __device__ __forceinline__

typedef const __attribute__((address_space(1))) void GV;
typedef __attribute__((address_space(3))) void LV;
DEV void gload16(const void* g, void* l) {
  __builtin_amdgcn_global_load_lds((GV*)g, (LV*)l, 16, 0, 0);
}

DEV ushort f2b(float x) {                       // f32 -> bf16 RNE
  union { float f; uint32_t u; } v; v.f = x;
  uint32_t r = v.u + 0x7FFFu + ((v.u >> 16) & 1u);
  return (ushort)(r >> 16);
}
DEV float b2f(ushort x) {
  union { uint32_t u; float f; } v; v.u = ((uint32_t)x) << 16; return v.f;
}
DEV float sigf(float x) { return 1.f / (1.f + __expf(-x)); }
DEV float tanh_fast(float x) {
  float xc = fminf(9.f, fmaxf(-9.f, x));
  float e = __expf(2.f * xc);
  return (e - 1.f) / (e + 1.f);
}

// ---------------------------------------------------------------------------
__global__ void k_convw(const float* __restrict__ src, ushort* __restrict__ dst,
                        int sr, int dr, int sc, int dc,
                        const float* __restrict__ scale, int mode) {
  long n = (long)dr * dc;
  for (long idx = (long)blockIdx.x * blockDim.x + threadIdx.x; idx < n;
       idx += (long)gridDim.x * blockDim.x) {
    int r = (int)(idx / dc), c = (int)(idx % dc);
    float v = 0.f;
    if (r < sr && c < sc) {
      v = src[(long)r * sc + c];
      if (mode == 1) v *= sigf(scale[c]);
    }
    dst[idx] = f2b(v);
  }
}

__global__ void k_vadd(const float* __restrict__ a, const float* __restrict__ b,
                       float* __restrict__ o, int n) {
  int i = blockIdx.x * blockDim.x + threadIdx.x;
  if (i < n) o[i] = a[i] + b[i];
}

// ---------------------------------------------------------------------------
// quantum evolution: 32 lanes per sample, Taylor action of expm, 6 terms
// ---------------------------------------------------------------------------
__global__ __launch_bounds__(128)
void k_quantum(const float* __restrict__ ampr_in, const float* __restrict__ ampi_in,
               const float* __restrict__ Hre, const float* __restrict__ Him,
               const float* __restrict__ mf,
               ushort* __restrict__ bio, float* __restrict__ ampr_out,
               float* __restrict__ ampi_out) {
  const int gid = blockIdx.x * 128 + threadIdx.x;
  const int b = gid >> 5;          // sample
  const int l32 = gid & 31;
  const int i = l32 & 15;          // row
  const int h = l32 >> 4;          // column half
  float hre[8], him[8];
#pragma unroll
  for (int jj = 0; jj < 8; jj++) {
    hre[jj] = Hre[i * 16 + h * 8 + jj];
    him[jj] = Him[i * 16 + h * 8 + jj];
  }
  const float mfi = mf[(long)b * 512 + i];
  float are = ampr_in[b * 16 + i], aim = ampi_in[b * 16 + i];
  float ss = are * are + aim * aim;
#pragma unroll
  for (int m = 1; m < 32; m <<= 1) ss += __shfl_xor(ss, m, 32);
  ss *= 0.5f;
  const float inv = 1.f / sqrtf(ss);
  are *= inv; aim *= inv;
#pragma unroll 1
  for (int st = 0; st < 100; ++st) {
    const float t = (float)st * 0.01f;
    const float fac = 1.f + t * mfi;
    const float dec = __expf(-t * 0.02f);   // exp(-t/50)
    float tre = are, tim = aim, rre = are, rim = aim;
#pragma unroll 1
    for (int k = 1; k <= 6; k++) {
      float w1r = 0.f, w1i = 0.f, w2r = 0.f, w2i = 0.f;
#pragma unroll
      for (int jj = 0; jj < 8; jj++) {
        const float vr = __shfl(tre, h * 8 + jj, 32);
        const float vi = __shfl(tim, h * 8 + jj, 32);
        w1r += hre[jj] * vr; w1i += hre[jj] * vi;
        w2r += him[jj] * vr; w2i += him[jj] * vi;
      }
      w1r += __shfl_xor(w1r, 16, 32);
      w1i += __shfl_xor(w1i, 16, 32);
      w2r += __shfl_xor(w2r, 16, 32);
      w2i += __shfl_xor(w2i, 16, 32);
      const float hr = w1r * fac - w2i;      // (Ht v)_re
      const float hi = w1i * fac + w2r;      // (Ht v)_im
      const float sk = 0.01f / (float)k;     // DT/k ; term *= -i*sk
      tre = sk * hi; tim = -sk * hr;
      rre += tre; rim += tim;
    }
    are = rre * dec; aim = rim * dec;
  }
  if (h == 0) {
    ampr_out[b * 16 + i] = are;
    ampi_out[b * 16 + i] = aim;
    bio[(long)b * 576 + i] = f2b(are * are + aim * aim);   // obs
  }
}

__global__ void k_biofill(const float* __restrict__ mf, ushort* __restrict__ bio) {
  long i = (long)blockIdx.x * blockDim.x + threadIdx.x;
  if (i < (long)2048 * 512) {
    long b = i >> 9, k = i & 511;
    bio[b * 576 + 16 + k] = f2b(mf[i]);
  }
}

// ---------------------------------------------------------------------------
// m97-structure bf16 MFMA GEMM (cached C-writes)
// ---------------------------------------------------------------------------
template<int BT>
__global__ __launch_bounds__(256)
void k_gemm(const ushort* __restrict__ A, int lda,
            const ushort* __restrict__ W, int ldw,
            const float* __restrict__ bias,
            const float* __restrict__ Gg, int t0,
            float* __restrict__ Cf, int ldcf,
            ushort* __restrict__ Cb, int ldcb,
            int N, int K, int act) {
  constexpr int FR = BT / 32;
  constexpr int CH = BT / 32;
  __shared__ __align__(16) ushort lsA[BT * 64];
  __shared__ __align__(16) ushort lsB[BT * 64];
  const int tid = threadIdx.x;
  const int lane = tid & 63, w = tid >> 6;
  const int lr = lane & 15, lq = lane >> 4;
  const int wm = (w >> 1) * (BT / 2), wn = (w & 1) * (BT / 2);
  const int bm = blockIdx.y * BT, bn = blockIdx.x * BT;
  const int srow = lane >> 3;
  const int scol = (lane & 7) * 8;

  f32x4 acc[FR][FR];
#pragma unroll
  for (int i = 0; i < FR; i++)
#pragma unroll
    for (int j = 0; j < FR; j++) acc[i][j] = (f32x4){0.f, 0.f, 0.f, 0.f};

  for (int kk = 0; kk < K; kk += 64) {
#pragma unroll
    for (int c = 0; c < CH; c++) {
      const int ch = w * CH + c;
      const int r = ch * 8 + srow;
      gload16(A + (size_t)(bm + r) * lda + kk + scol, lsA + ch * 512);
      gload16(W + (size_t)(bn + r) * ldw + kk + scol, lsB + ch * 512);
    }
    __syncthreads();
    short8 af[FR][2], bf[FR][2];
#pragma unroll
    for (int mi = 0; mi < FR; mi++)
#pragma unroll
      for (int k2 = 0; k2 < 2; k2++)
        af[mi][k2] = *(const short8*)(lsA + (wm + mi * 16 + lr) * 64 + k2 * 32 + lq * 8);
#pragma unroll
    for (int ni = 0; ni < FR; ni++)
#pragma unroll
      for (int k2 = 0; k2 < 2; k2++)
        bf[ni][k2] = *(const short8*)(lsB + (wn + ni * 16 + lr) * 64 + k2 * 32 + lq * 8);
#pragma unroll
    for (int k2 = 0; k2 < 2; k2++)
#pragma unroll
      for (int mi = 0; mi < FR; mi++)
#pragma unroll
        for (int ni = 0; ni < FR; ni++)
          acc[mi][ni] = __builtin_amdgcn_mfma_f32_16x16x32_bf16(
              af[mi][k2], bf[ni][k2], acc[mi][ni], 0, 0, 0);
    __syncthreads();
  }

#pragma unroll
  for (int mi = 0; mi < FR; mi++) {
#pragma unroll
    for (int r = 0; r < 4; r++) {
      const int row = bm + wm + mi * 16 + lq * 4 + r;
      float gfac = 0.f; const float* ggrow = nullptr;
      if (Gg) {
        gfac = __expf(-(float)(t0 + (row >> 11)) * 0.1f);   // adapt(t)
        ggrow = Gg + (size_t)(row & 2047) * 1024;
      }
#pragma unroll
      for (int ni = 0; ni < FR; ni++) {
        const int col = bn + wn + ni * 16 + lr;
        if (col < N) {
          float v = acc[mi][ni][r];
          if (bias) v += bias[col];
          if (Gg)  v += gfac * ggrow[col];
          if (act == 1) v = fmaxf(v, 0.f);
          else if (act == 2) v = tanh_fast(v);
          else if (act == 3) v = sigf(v);
          if (Cf) Cf[(size_t)row * ldcf + col] = v;
          if (Cb) Cb[(size_t)row * ldcb + col] = f2b(v);
        }
      }
    }
  }
}

// ---------------------------------------------------------------------------
__global__ void k_noiseconv(const float* __restrict__ noise, ushort* __restrict__ dst, int t0) {
  long n = 10L * 2048 * 448;
  for (long idx = (long)blockIdx.x * blockDim.x + threadIdx.x; idx < n;
       idx += (long)gridDim.x * blockDim.x) {
    int r = (int)(idx % 448);
    long row = idx / 448;
    int b = (int)(row & 2047);
    int tl = (int)(row >> 11);
    ushort v = 0;
    if (r < 400)
      v = f2b(__builtin_nontemporal_load(&noise[((long)b * 50 + t0 + tl) * 400 + r]));
    dst[idx] = v;
  }
}

// ---------------------------------------------------------------------------
// Column-split LSTM layer chunk: 10 timesteps, internal grid sync.
// 256 WGs x 256 thr (4 waves, 1 wave/SIMD -> 512-VGPR budget).
// WG (sg,cg): samples [sg*128,+128), unit-cols [cg*16,+16) across all 4 gates.
// Whh slice (64 rows x 256) register-resident: wres[4][8] = 128 VGPRs.
// h ping-pongs between global hbA/hbB (bf16); c stays in registers, spilled
// to CST only across launches. Grid barrier: release-add / relaxed-spin /
// acquire on barc (agent scope).
// ---------------------------------------------------------------------------
__global__ __launch_bounds__(256, 1)
void k_layer(const ushort* __restrict__ IH, const ushort* __restrict__ Whh,
             ushort* __restrict__ hbA, ushort* __restrict__ hbB,
             float* __restrict__ cstate, int* __restrict__ barc,
             ushort* __restrict__ Hout, float* __restrict__ Xout, int t0) {
  const int wg = blockIdx.x;
  const int sg = wg >> 4;            // 16 sample-groups x 128
  const int cg = wg & 15;            // 16 col-groups x 16
  const int tid = threadIdx.x;
  const int lane = tid & 63, wv = tid >> 6;   // 4 waves
  const int lr = lane & 15, lq = lane >> 4;
  const int sbase = sg * 128 + wv * 32;
  const int j = cg * 16 + lr;        // unit col (B-row for MFMA, col in gate phase)

  // register-resident Whh slice: wres[g][kk] = Whh[g*256+j][kk*32+lq*8 ..+8)
  short8 wres[4][8];
#pragma unroll
  for (int g = 0; g < 4; g++) {
    const ushort* wp = Whh + (size_t)(g * 256 + j) * 256 + lq * 8;
#pragma unroll
    for (int kk = 0; kk < 8; kk++) wres[g][kk] = *(const short8*)(wp + kk * 32);
  }

  // c state: samples sbase + mi*16 + lq*4 + r, col j
  float c_reg[2][4];
#pragma unroll
  for (int mi = 0; mi < 2; mi++)
#pragma unroll
    for (int r = 0; r < 4; r++)
      c_reg[mi][r] = cstate[(size_t)(sbase + mi * 16 + lq * 4 + r) * 256 + j];

  for (int tl = 0; tl < 10; ++tl) {
    const ushort* hin = (tl & 1) ? hbB : hbA;
    ushort* hout = (tl & 1) ? hbA : hbB;

    f32x4 acc[2][4];
#pragma unroll
    for (int mi = 0; mi < 2; mi++)
#pragma unroll
      for (int g = 0; g < 4; g++) acc[mi][g] = (f32x4){0.f, 0.f, 0.f, 0.f};

#pragma unroll
    for (int kk = 0; kk < 8; kk++) {
      const short8 a0 = *(const short8*)(hin + (size_t)(sbase + lr) * 256 + kk * 32 + lq * 8);
      const short8 a1 = *(const short8*)(hin + (size_t)(sbase + 16 + lr) * 256 + kk * 32 + lq * 8);
#pragma unroll
      for (int g = 0; g < 4; g++) {
        acc[0][g] = __builtin_amdgcn_mfma_f32_16x16x32_bf16(a0, wres[g][kk], acc[0][g], 0, 0, 0);
        acc[1][g] = __builtin_amdgcn_mfma_f32_16x16x32_bf16(a1, wres[g][kk], acc[1][g], 0, 0, 0);
      }
    }

    const int t = t0 + tl;
#pragma unroll
    for (int mi = 0; mi < 2; mi++) {
#pragma unroll
      for (int r = 0; r < 4; r++) {
        const int s = sbase + mi * 16 + lq * 4 + r;
        const size_t ihb = ((size_t)tl * 2048 + s) * 1024;
        const float zi = acc[mi][0][r] + b2f(IH[ihb + j]);
        const float zf = acc[mi][1][r] + b2f(IH[ihb + 256 + j]);
        const float zg = acc[mi][2][r] + b2f(IH[ihb + 512 + j]);
        const float zo = acc[mi][3][r] + b2f(IH[ihb + 768 + j]);
        const float ig = sigf(zi), fg = sigf(zf), gg = tanh_fast(zg), og = sigf(zo);
        const float c = fg * c_reg[mi][r] + ig * gg;
        c_reg[mi][r] = c;
        const float h = og * tanh_fast(c);
        hout[(size_t)s * 256 + j] = f2b(h);
        if (Hout) Hout[((size_t)t * 2048 + s) * 256 + j] = f2b(h);
        if (Xout)
          __builtin_nontemporal_store(h, &Xout[((size_t)s * 50 + t) * 256 + j]);
      }
    }

    // grid barrier between steps (not after the last: epilogue is WG-local)
    if (tl < 9) {
      __syncthreads();               // all waves' stores drained (vmcnt in barrier)
      if (tid == 0) {
        __hip_atomic_fetch_add(barc, 1, __ATOMIC_RELEASE, __HIP_MEMORY_SCOPE_AGENT);
        const int target = 256 * (tl + 1);
        while (__hip_atomic_load(barc, __ATOMIC_RELAXED, __HIP_MEMORY_SCOPE_AGENT) < target)
          __builtin_amdgcn_s_sleep(8);
        (void)__hip_atomic_load(barc, __ATOMIC_ACQUIRE, __HIP_MEMORY_SCOPE_AGENT);
      }
      __syncthreads();
    }
  }

#pragma unroll
  for (int mi = 0; mi < 2; mi++)
#pragma unroll
    for (int r = 0; r < 4; r++)
      cstate[(size_t)(sbase + mi * 16 + lq * 4 + r) * 256 + j] = c_reg[mi][r];
}

// ---------------------------------------------------------------------------
// consumer-feature concat: cf = [hT (bf16) | receptor (bf16)] padded
// ---------------------------------------------------------------------------
__global__ void k_cffill(const ushort* __restrict__ hT, const ushort* __restrict__ recb,
                         ushort* __restrict__ cf) {
  long i = (long)blockIdx.x * blockDim.x + threadIdx.x;
  if (i < (long)2048 * 656) {
    long b = i / 656; int c = (int)(i % 656);
    cf[b * 704 + c] = (c < 256) ? hT[b * 256 + c] : recb[b * 448 + (c - 256)];
  }
}

__global__ __launch_bounds__(256)
void k_cons(const float* __restrict__ c3, const float* __restrict__ w4,
            const float* __restrict__ b4, float* __restrict__ out) {
  __shared__ float red[256];
  float accv = 0.f;
  for (int b = threadIdx.x; b < 2048; b += 256) {
    float d = b4[0];
#pragma unroll
    for (int k = 0; k < 64; k++) d += c3[(long)b * 64 + k] * w4[k];
    accv += sigf(d);
  }
  red[threadIdx.x] = accv; __syncthreads();
  for (int s = 128; s > 0; s >>= 1) {
    if (threadIdx.x < s) red[threadIdx.x] += red[threadIdx.x + s];
    __syncthreads();
  }
  if (threadIdx.x == 0) out[0] = red[0] * (1.f / 2048.f);
}

__global__ __launch_bounds__(256)
void k_val(const float* __restrict__ x, float* __restrict__ out) {
  __shared__ float red[256];
  const float* p = x + (size_t)blockIdx.x * 12800;
  float a = 0.f;
  for (int i = threadIdx.x; i < 12800; i += 256) a += tanh_fast(p[i]);
  red[threadIdx.x] = a; __syncthreads();
  for (int s = 128; s > 0; s >>= 1) {
    if (threadIdx.x < s) red[threadIdx.x] += red[threadIdx.x + s];
    __syncthreads();
  }
  if (threadIdx.x == 0) out[blockIdx.x] = red[0] * (1.f / 12800.f);
}

// ---------------------------------------------------------------------------
// entanglement entropy: in-register unrolled 8x8 Jacobi
// ---------------------------------------------------------------------------
__global__ __launch_bounds__(64)
void k_ent(const float* __restrict__ ar, const float* __restrict__ ai,
           float* __restrict__ partial) {
  __shared__ float red[64];
  const int tid = threadIdx.x;
  const int b = blockIdx.x * 64 + tid;
  float vr[16], vi[16];
#pragma unroll
  for (int i = 0; i < 16; i++) { vr[i] = ar[b * 16 + i]; vi[i] = ai[b * 16 + i]; }
  float m[64];   // 8x8, compile-time indexed only -> registers
#pragma unroll
  for (int j = 0; j < 4; j++)
#pragma unroll
    for (int k = 0; k < 4; k++) {
      float re = 0.f, im = 0.f;
#pragma unroll
      for (int i = 0; i < 4; i++) {
        float xr = vr[i * 4 + j], xi = vi[i * 4 + j];
        float yr = vr[i * 4 + k], yi = vi[i * 4 + k];
        re += xr * yr + xi * yi;
        im += xi * yr - xr * yi;
      }
      m[j * 8 + k] = re;
      m[j * 8 + (k + 4)] = -im;
      m[(j + 4) * 8 + k] = im;
      m[(j + 4) * 8 + (k + 4)] = re;
    }
#pragma unroll 1
  for (int sweep = 0; sweep < 6; ++sweep) {
#pragma unroll
    for (int p = 0; p < 7; p++) {
#pragma unroll
      for (int q = p + 1; q < 8; q++) {
        const float apq = m[p * 8 + q];
        if (fabsf(apq) > 1e-28f) {
          const float app = m[p * 8 + p], aqq = m[q * 8 + q];
          const float tau = (aqq - app) / (2.f * apq);
          const float tt = (tau >= 0.f ? 1.f : -1.f) /
                           (fabsf(tau) + sqrtf(1.f + tau * tau));
          const float cc = 1.f / sqrtf(1.f + tt * tt);
          const float ssn = tt * cc;
#pragma unroll
          for (int k2 = 0; k2 < 8; k2++) {
            const float mp = m[p * 8 + k2], mq = m[q * 8 + k2];
            m[p * 8 + k2] = cc * mp - ssn * mq;
            m[q * 8 + k2] = ssn * mp + cc * mq;
          }
#pragma unroll
          for (int k2 = 0; k2 < 8; k2++) {
            const float mp = m[k2 * 8 + p], mq = m[k2 * 8 + q];
            m[k2 * 8 + p] = cc * mp - ssn * mq;
            m[k2 * 8 + q] = ssn * mp + cc * mq;
          }
        }
      }
    }
  }
  float e = 0.f;
#pragma unroll
  for (int k2 = 0; k2 < 8; k2++) {
    const float lam = fmaxf(m[k2 * 8 + k2], 1e-12f);
    e -= lam * logf(lam);
  }
  red[tid] = e; __syncthreads();
  for (int s = 32; s > 0; s >>= 1) {
    if (tid < s) red[tid] += red[tid + s];
    __syncthreads();
  }
  if (tid == 0) partial[blockIdx.x] = red[0];
}

__global__ void k_entfin(const float* __restrict__ partial, float* __restrict__ out) {
  if (threadIdx.x == 0) {
    float s = 0.f;
    for (int i = 0; i < 32; i++) s += partial[i];
    out[0] = s * (0.5f / 2048.f);
  }
}

// ---------------------------------------------------------------------------
extern "C" void kernel_launch(void* const* d_in, const int* in_sizes, int n_in,
                              void* d_out, int out_size, void* d_ws, size_t ws_size,
                              hipStream_t stream) {
  (void)in_sizes; (void)n_in; (void)out_size; (void)ws_size;
  const float* mf    = (const float*)d_in[0];
  const float* noise = (const float*)d_in[1];
  const float* ampr  = (const float*)d_in[2];
  const float* ampi  = (const float*)d_in[3];
  const float* Hre   = (const float*)d_in[4];
  const float* Him   = (const float*)d_in[5];
  const float* gpc   = (const float*)d_in[6];
  const float* bw1 = (const float*)d_in[7];  const float* bb1 = (const float*)d_in[8];
  const float* bw2 = (const float*)d_in[9];  const float* bb2 = (const float*)d_in[10];
  const float* bw3 = (const float*)d_in[11]; const float* bb3 = (const float*)d_in[12];
  const float* Wih[3] = {(const float*)d_in[13], (const float*)d_in[17], (const float*)d_in[21]};
  const float* Whh[3] = {(const float*)d_in[14], (const float*)d_in[18], (const float*)d_in[22]};
  const float* bih[3] = {(const float*)d_in[15], (const float*)d_in[19], (const float*)d_in[23]};
  const float* bhh[3] = {(const float*)d_in[16], (const float*)d_in[20], (const float*)d_in[24]};
  const float* cw1 = (const float*)d_in[25]; const float* cb1 = (const float*)d_in[26];
  const float* cw2 = (const float*)d_in[27]; const float* cb2 = (const float*)d_in[28];
  const float* cw3 = (const float*)d_in[29]; const float* cb3 = (const float*)d_in[30];
  const float* cw4 = (const float*)d_in[31]; const float* cb4 = (const float*)d_in[32];

  float* out = (float*)d_out;
  float* out_rec  = out;                    // [2048][400]
  float* out_seq  = out + 819200;           // [2048][50][256]
  float* out_val  = out + 27033600;         // [2048]
  float* out_cons = out + 27035648;
  float* out_ent  = out + 27035649;

  char* ws = (char*)d_ws;
  size_t off = 0;
  auto alloc = [&](size_t bytes) -> char* {
    char* p = ws + off; off += (bytes + 255) & ~(size_t)255; return p;
  };
  ushort* WB1   = (ushort*)alloc((size_t)256 * 576 * 2);
  ushort* WB2   = (ushort*)alloc((size_t)128 * 256 * 2);
  ushort* WB3   = (ushort*)alloc((size_t)512 * 128 * 2);
  ushort* WIH0  = (ushort*)alloc((size_t)1024 * 448 * 2);
  ushort* WIH0S = (ushort*)alloc((size_t)1024 * 448 * 2);
  ushort* WIH1  = (ushort*)alloc((size_t)1024 * 256 * 2);
  ushort* WIH2  = (ushort*)alloc((size_t)1024 * 256 * 2);
  ushort* WHH0  = (ushort*)alloc((size_t)1024 * 256 * 2);
  ushort* WHH1  = (ushort*)alloc((size_t)1024 * 256 * 2);
  ushort* WHH2  = (ushort*)alloc((size_t)1024 * 256 * 2);
  ushort* WC1   = (ushort*)alloc((size_t)512 * 704 * 2);
  ushort* WC2   = (ushort*)alloc((size_t)256 * 512 * 2);
  ushort* WC3   = (ushort*)alloc((size_t)128 * 256 * 2);
  float*  BSUM  = (float*)alloc((size_t)3 * 1024 * 4);
  ushort* BIO   = (ushort*)alloc((size_t)2048 * 576 * 2);
  ushort* H1B   = (ushort*)alloc((size_t)2048 * 256 * 2);
  ushort* H2B   = (ushort*)alloc((size_t)2048 * 128 * 2);
  ushort* RECB  = (ushort*)alloc((size_t)2048 * 448 * 2);
  float*  GG    = (float*)alloc((size_t)2048 * 1024 * 4);
  float*  AMPR  = (float*)alloc((size_t)2048 * 16 * 4);
  float*  AMPI  = (float*)alloc((size_t)2048 * 16 * 4);
  ushort* NCH   = (ushort*)alloc((size_t)10 * 2048 * 448 * 2);
  ushort* IHC   = (ushort*)alloc((size_t)10 * 2048 * 1024 * 2);
  ushort* HBUF  = (ushort*)alloc((size_t)50 * 2048 * 256 * 2);
  ushort* HBA   = (ushort*)alloc((size_t)2048 * 256 * 2);
  ushort* HBB   = (ushort*)alloc((size_t)2048 * 256 * 2);
  float*  CST   = (float*)alloc((size_t)2048 * 256 * 4);
  int*    BARC  = (int*)alloc(256);
  ushort* CFB   = (ushort*)alloc((size_t)2048 * 704 * 2);
  ushort* C1B   = (ushort*)alloc((size_t)2048 * 512 * 2);
  ushort* C2B   = (ushort*)alloc((size_t)2048 * 256 * 2);
  float*  C3F   = (float*)alloc((size_t)2048 * 64 * 4);
  float*  ENTP  = (float*)alloc((size_t)32 * 4);

  hipMemsetAsync(BIO,  0, (size_t)2048 * 576 * 2, stream);
  hipMemsetAsync(RECB, 0, (size_t)2048 * 448 * 2, stream);
  hipMemsetAsync(CFB,  0, (size_t)2048 * 704 * 2, stream);

  auto convw = [&](const float* src, ushort* dst, int sr, int dr, int sc, int dc,
                   const float* scale, int mode) {
    long n = (long)dr * dc;
    int blocks = (int)((n + 255) / 256); if (blocks > 2048) blocks = 2048;
    hipLaunchKernelGGL(k_convw, dim3(blocks), dim3(256), 0, stream,
                       src, dst, sr, dr, sc, dc, scale, mode);
  };
  convw(bw1, WB1, 256, 256, 528, 576, nullptr, 0);
  convw(bw2, WB2, 128, 128, 256, 256, nullptr, 0);
  convw(bw3, WB3, 400, 512, 128, 128, nullptr, 0);
  convw(Wih[0], WIH0,  1024, 1024, 400, 448, nullptr, 0);
  convw(Wih[0], WIH0S, 1024, 1024, 400, 448, gpc, 1);   // fold sigmoid(gpc)
  convw(Wih[1], WIH1, 1024, 1024, 256, 256, nullptr, 0);
  convw(Wih[2], WIH2, 1024, 1024, 256, 256, nullptr, 0);
  convw(Whh[0], WHH0, 1024, 1024, 256, 256, nullptr, 0);
  convw(Whh[1], WHH1, 1024, 1024, 256, 256, nullptr, 0);
  convw(Whh[2], WHH2, 1024, 1024, 256, 256, nullptr, 0);
  convw(cw1, WC1, 512, 512, 656, 704, nullptr, 0);
  convw(cw2, WC2, 256, 256, 512, 512, nullptr, 0);
  convw(cw3, WC3,  64, 128, 256, 256, nullptr, 0);
  for (int l = 0; l < 3; l++)
    hipLaunchKernelGGL(k_vadd, dim3(4), dim3(256), 0, stream, bih[l], bhh[l], BSUM + l * 1024, 1024);

  hipLaunchKernelGGL(k_quantum, dim3(512), dim3(128), 0, stream,
                     ampr, ampi, Hre, Him, mf, BIO, AMPR, AMPI);
  hipLaunchKernelGGL(k_biofill, dim3(4096), dim3(256), 0, stream, mf, BIO);

  auto gemm = [&](bool big, const ushort* A, int lda, const ushort* W, int ldw,
                  const float* bias, const float* Gg, int t0, float* Cf, int ldcf,
                  ushort* Cb, int ldcb, int M, int N, int K, int act) {
    if (big) {
      dim3 grid((N + 127) / 128, M / 128);
      hipLaunchKernelGGL(k_gemm<128>, grid, dim3(256), 0, stream,
                         A, lda, W, ldw, bias, Gg, t0, Cf, ldcf, Cb, ldcb, N, K, act);
    } else {
      dim3 grid((N + 63) / 64, M / 64);
      hipLaunchKernelGGL(k_gemm<64>, grid, dim3(256), 0, stream,
                         A, lda, W, ldw, bias, Gg, t0, Cf, ldcf, Cb, ldcb, N, K, act);
    }
  };

  // receptor MLP
  gemm(false, BIO, 576, WB1, 576, bb1, nullptr, 0, nullptr, 0, H1B, 256, 2048, 256, 576, 1);
  gemm(false, H1B, 256, WB2, 256, bb2, nullptr, 0, nullptr, 0, H2B, 128, 2048, 128, 256, 2);
  gemm(false, H2B, 128, WB3, 128, bb3, nullptr, 0, out_rec, 400, RECB, 448, 2048, 400, 128, 3);
  // Gg = (receptor * sigmoid(gpc)) @ Wih0^T
  gemm(false, RECB, 448, WIH0S, 448, nullptr, nullptr, 0, GG, 1024, nullptr, 0, 2048, 1024, 448, 0);

  // 3-layer LSTM, chunked 10 timesteps, column-split recurrence w/ grid sync
  for (int l = 0; l < 3; l++) {
    hipMemsetAsync(HBA, 0, (size_t)2048 * 256 * 2, stream);   // h = 0
    hipMemsetAsync(CST, 0, (size_t)2048 * 256 * 4, stream);   // c = 0
    for (int c = 0; c < 5; c++) {
      int t0 = c * 10;
      if (l == 0) {
        hipLaunchKernelGGL(k_noiseconv, dim3(8192), dim3(256), 0, stream, noise, NCH, t0);
        gemm(true, NCH, 448, WIH0, 448, BSUM, GG, t0, nullptr, 0, IHC, 1024, 20480, 1024, 448, 0);
      } else {
        const ushort* Aip = HBUF + (size_t)t0 * 2048 * 256;
        gemm(true, Aip, 256, (l == 1 ? WIH1 : WIH2), 256, BSUM + l * 1024, nullptr, 0,
             nullptr, 0, IHC, 1024, 20480, 1024, 256, 0);
      }
      hipMemsetAsync(BARC, 0, 4, stream);
      hipLaunchKernelGGL(k_layer, dim3(256), dim3(256), 0, stream,
                         IHC, (l == 0 ? WHH0 : l == 1 ? WHH1 : WHH2),
                         HBA, HBB, CST, BARC,
                         (l < 2 ? HBUF : (ushort*)nullptr),
                         (l == 2 ? out_seq : (float*)nullptr), t0);
    }
  }

  // consumer MLP (hT now lives in HBA as bf16 after the final chunk)
  hipLaunchKernelGGL(k_cffill, dim3(5256), dim3(256), 0, stream, HBA, RECB, CFB);
  gemm(false, CFB, 704, WC1, 704, cb1, nullptr, 0, nullptr, 0, C1B, 512, 2048, 512, 704, 1);
  gemm(false, C1B, 512, WC2, 512, cb2, nullptr, 0, nullptr, 0, C2B, 256, 2048, 256, 512, 1);
  gemm(false, C2B, 256, WC3, 256, cb3, nullptr, 0, C3F, 64, nullptr, 0, 2048, 64, 256, 2);
  hipLaunchKernelGGL(k_cons, dim3(1), dim3(256), 0, stream, C3F, cw4, cb4, out_cons);

  // valence + entropy
  hipLaunchKernelGGL(k_val, dim3(2048), dim3(256), 0, stream, out_seq, out_val);
  hipLaunchKernelGGL(k_ent, dim3(32), dim3(64), 0, stream, AMPR, AMPI, ENTP);
  hipLaunchKernelGGL(k_entfin, dim3(1), dim3(32), 0, stream, ENTP, out_ent);
}

// Round 12
// 3355.205 us; speedup vs baseline: 1.3721x; 1.3721x over previous
//
#include <hip/hip_runtime.h>
#include <stdint.h>

// ---------------------------------------------------------------------------
// QuantumOlfactoryReceptor: full pipeline
// Round 12: k_rec with BLOCK-STAGED IH (4 steps = 128 KB LDS per burst).
//  Model (from R3+R11 FETCH evidence): per-step IH staging streams 4MB through
//  each 4MB XCD-L2 -> flushes Whh every step -> 40MB/launch HBM weight
//  re-fetch (10us/step, the 8-experiment plateau). Block-staging leaves L2
//  undisturbed for 3 of 4 steps -> Whh L2-resident -> ~3.7us/step L2-bound.
//  Everything else = best-known ensemble (R4 quantum, R9 ent, R4 rec base).
// ---------------------------------------------------------------------------

using short8 = __attribute__((ext_vector_type(8))) short;
using f32x4  = __attribute__((ext_vector_type(4))) float;

#define DEV static __device__ __forceinline__

typedef const __attribute__((address_space(1))) void GV;
typedef __attribute__((address_space(3))) void LV;
DEV void gload16(const void* g, void* l) {
  __builtin_amdgcn_global_load_lds((GV*)g, (LV*)l, 16, 0, 0);
}

DEV ushort f2b(float x) {                       // f32 -> bf16 RNE
  union { float f; uint32_t u; } v; v.f = x;
  uint32_t r = v.u + 0x7FFFu + ((v.u >> 16) & 1u);
  return (ushort)(r >> 16);
}
DEV float b2f(ushort x) {
  union { uint32_t u; float f; } v; v.u = ((uint32_t)x) << 16; return v.f;
}
DEV float sigf(float x) { return 1.f / (1.f + __expf(-x)); }
DEV float tanh_fast(float x) {
  float xc = fminf(9.f, fmaxf(-9.f, x));
  float e = __expf(2.f * xc);
  return (e - 1.f) / (e + 1.f);
}

// ---------------------------------------------------------------------------
__global__ void k_convw(const float* __restrict__ src, ushort* __restrict__ dst,
                        int sr, int dr, int sc, int dc,
                        const float* __restrict__ scale, int mode) {
  long n = (long)dr * dc;
  for (long idx = (long)blockIdx.x * blockDim.x + threadIdx.x; idx < n;
       idx += (long)gridDim.x * blockDim.x) {
    int r = (int)(idx / dc), c = (int)(idx % dc);
    float v = 0.f;
    if (r < sr && c < sc) {
      v = src[(long)r * sc + c];
      if (mode == 1) v *= sigf(scale[c]);
    }
    dst[idx] = f2b(v);
  }
}

__global__ void k_vadd(const float* __restrict__ a, const float* __restrict__ b,
                       float* __restrict__ o, int n) {
  int i = blockIdx.x * blockDim.x + threadIdx.x;
  if (i < n) o[i] = a[i] + b[i];
}

// ---------------------------------------------------------------------------
// quantum evolution: 32 lanes per sample, Taylor action of expm, 6 terms
// ---------------------------------------------------------------------------
__global__ __launch_bounds__(128)
void k_quantum(const float* __restrict__ ampr_in, const float* __restrict__ ampi_in,
               const float* __restrict__ Hre, const float* __restrict__ Him,
               const float* __restrict__ mf,
               ushort* __restrict__ bio, float* __restrict__ ampr_out,
               float* __restrict__ ampi_out) {
  const int gid = blockIdx.x * 128 + threadIdx.x;
  const int b = gid >> 5;          // sample
  const int l32 = gid & 31;
  const int i = l32 & 15;          // row
  const int h = l32 >> 4;          // column half
  float hre[8], him[8];
#pragma unroll
  for (int jj = 0; jj < 8; jj++) {
    hre[jj] = Hre[i * 16 + h * 8 + jj];
    him[jj] = Him[i * 16 + h * 8 + jj];
  }
  const float mfi = mf[(long)b * 512 + i];
  float are = ampr_in[b * 16 + i], aim = ampi_in[b * 16 + i];
  float ss = are * are + aim * aim;
#pragma unroll
  for (int m = 1; m < 32; m <<= 1) ss += __shfl_xor(ss, m, 32);
  ss *= 0.5f;
  const float inv = 1.f / sqrtf(ss);
  are *= inv; aim *= inv;
#pragma unroll 1
  for (int st = 0; st < 100; ++st) {
    const float t = (float)st * 0.01f;
    const float fac = 1.f + t * mfi;
    const float dec = __expf(-t * 0.02f);   // exp(-t/50)
    float tre = are, tim = aim, rre = are, rim = aim;
#pragma unroll 1
    for (int k = 1; k <= 6; k++) {
      float w1r = 0.f, w1i = 0.f, w2r = 0.f, w2i = 0.f;
#pragma unroll
      for (int jj = 0; jj < 8; jj++) {
        const float vr = __shfl(tre, h * 8 + jj, 32);
        const float vi = __shfl(tim, h * 8 + jj, 32);
        w1r += hre[jj] * vr; w1i += hre[jj] * vi;
        w2r += him[jj] * vr; w2i += him[jj] * vi;
      }
      w1r += __shfl_xor(w1r, 16, 32);
      w1i += __shfl_xor(w1i, 16, 32);
      w2r += __shfl_xor(w2r, 16, 32);
      w2i += __shfl_xor(w2i, 16, 32);
      const float hr = w1r * fac - w2i;      // (Ht v)_re
      const float hi = w1i * fac + w2r;      // (Ht v)_im
      const float sk = 0.01f / (float)k;     // DT/k ; term *= -i*sk
      tre = sk * hi; tim = -sk * hr;
      rre += tre; rim += tim;
    }
    are = rre * dec; aim = rim * dec;
  }
  if (h == 0) {
    ampr_out[b * 16 + i] = are;
    ampi_out[b * 16 + i] = aim;
    bio[(long)b * 576 + i] = f2b(are * are + aim * aim);   // obs
  }
}

__global__ void k_biofill(const float* __restrict__ mf, ushort* __restrict__ bio) {
  long i = (long)blockIdx.x * blockDim.x + threadIdx.x;
  if (i < (long)2048 * 512) {
    long b = i >> 9, k = i & 511;
    bio[b * 576 + 16 + k] = f2b(mf[i]);
  }
}

// ---------------------------------------------------------------------------
// m97-structure bf16 MFMA GEMM (cached C-writes)
// ---------------------------------------------------------------------------
template<int BT>
__global__ __launch_bounds__(256)
void k_gemm(const ushort* __restrict__ A, int lda,
            const ushort* __restrict__ W, int ldw,
            const float* __restrict__ bias,
            const float* __restrict__ Gg, int t0,
            float* __restrict__ Cf, int ldcf,
            ushort* __restrict__ Cb, int ldcb,
            int N, int K, int act) {
  constexpr int FR = BT / 32;
  constexpr int CH = BT / 32;
  __shared__ __align__(16) ushort lsA[BT * 64];
  __shared__ __align__(16) ushort lsB[BT * 64];
  const int tid = threadIdx.x;
  const int lane = tid & 63, w = tid >> 6;
  const int lr = lane & 15, lq = lane >> 4;
  const int wm = (w >> 1) * (BT / 2), wn = (w & 1) * (BT / 2);
  const int bm = blockIdx.y * BT, bn = blockIdx.x * BT;
  const int srow = lane >> 3;
  const int scol = (lane & 7) * 8;

  f32x4 acc[FR][FR];
#pragma unroll
  for (int i = 0; i < FR; i++)
#pragma unroll
    for (int j = 0; j < FR; j++) acc[i][j] = (f32x4){0.f, 0.f, 0.f, 0.f};

  for (int kk = 0; kk < K; kk += 64) {
#pragma unroll
    for (int c = 0; c < CH; c++) {
      const int ch = w * CH + c;
      const int r = ch * 8 + srow;
      gload16(A + (size_t)(bm + r) * lda + kk + scol, lsA + ch * 512);
      gload16(W + (size_t)(bn + r) * ldw + kk + scol, lsB + ch * 512);
    }
    __syncthreads();
    short8 af[FR][2], bf[FR][2];
#pragma unroll
    for (int mi = 0; mi < FR; mi++)
#pragma unroll
      for (int k2 = 0; k2 < 2; k2++)
        af[mi][k2] = *(const short8*)(lsA + (wm + mi * 16 + lr) * 64 + k2 * 32 + lq * 8);
#pragma unroll
    for (int ni = 0; ni < FR; ni++)
#pragma unroll
      for (int k2 = 0; k2 < 2; k2++)
        bf[ni][k2] = *(const short8*)(lsB + (wn + ni * 16 + lr) * 64 + k2 * 32 + lq * 8);
#pragma unroll
    for (int k2 = 0; k2 < 2; k2++)
#pragma unroll
      for (int mi = 0; mi < FR; mi++)
#pragma unroll
        for (int ni = 0; ni < FR; ni++)
          acc[mi][ni] = __builtin_amdgcn_mfma_f32_16x16x32_bf16(
              af[mi][k2], bf[ni][k2], acc[mi][ni], 0, 0, 0);
    __syncthreads();
  }

#pragma unroll
  for (int mi = 0; mi < FR; mi++) {
#pragma unroll
    for (int r = 0; r < 4; r++) {
      const int row = bm + wm + mi * 16 + lq * 4 + r;
      float gfac = 0.f; const float* ggrow = nullptr;
      if (Gg) {
        gfac = __expf(-(float)(t0 + (row >> 11)) * 0.1f);   // adapt(t)
        ggrow = Gg + (size_t)(row & 2047) * 1024;
      }
#pragma unroll
      for (int ni = 0; ni < FR; ni++) {
        const int col = bn + wn + ni * 16 + lr;
        if (col < N) {
          float v = acc[mi][ni][r];
          if (bias) v += bias[col];
          if (Gg)  v += gfac * ggrow[col];
          if (act == 1) v = fmaxf(v, 0.f);
          else if (act == 2) v = tanh_fast(v);
          else if (act == 3) v = sigf(v);
          if (Cf) Cf[(size_t)row * ldcf + col] = v;
          if (Cb) Cb[(size_t)row * ldcb + col] = f2b(v);
        }
      }
    }
  }
}

// ---------------------------------------------------------------------------
__global__ void k_noiseconv(const float* __restrict__ noise, ushort* __restrict__ dst, int t0) {
  long n = 10L * 2048 * 448;
  for (long idx = (long)blockIdx.x * blockDim.x + threadIdx.x; idx < n;
       idx += (long)gridDim.x * blockDim.x) {
    int r = (int)(idx % 448);
    long row = idx / 448;
    int b = (int)(row & 2047);
    int tl = (int)(row >> 11);
    ushort v = 0;
    if (r < 400)
      v = f2b(__builtin_nontemporal_load(&noise[((long)b * 50 + t0 + tl) * 400 + r]));
    dst[idx] = v;
  }
}

// ---------------------------------------------------------------------------
// LSTM recurrence, 10 timesteps/launch. 128 WGs x 16 samples x 8 waves.
// Wave w owns unit-cols [w*32,w*32+32) for all 4 gates -> register-only cell
// update; gate-i weights register-resident. IH staged in BLOCKS of 4 steps
// (128 KB LDS burst) so the step loop issues no global IH traffic -> Whh
// stays L2-resident between bursts. LDS = 128 + 8.5 KB.
// ---------------------------------------------------------------------------
__global__ __launch_bounds__(512, 2)
void k_rec(const ushort* __restrict__ IH, const ushort* __restrict__ Whh,
           float* __restrict__ hstate, float* __restrict__ cstate,
           ushort* __restrict__ Hout, float* __restrict__ Xout, int t0) {
  __shared__ ushort h_lds[16][266];                      // odd dword stride
  __shared__ __align__(16) ushort ih_lds[4][16 * 1024];  // 4-step block, 128 KB
  const int tid = threadIdx.x;
  const int lane = tid & 63, w = tid >> 6;               // w in [0,8)
  const int lr = lane & 15, lq = lane >> 4;
  const int b0 = blockIdx.x * 16;
  const int wcols = w * 32;

  // resident gate-i weights: 2 col-groups x 8 k-chunks = 64 VGPRs
  short8 wres[2][8];
#pragma unroll
  for (int cg = 0; cg < 2; cg++) {
    const ushort* wp = Whh + (size_t)(wcols + cg * 16 + lr) * 256 + lq * 8;
#pragma unroll
    for (int kk = 0; kk < 8; kk++) wres[cg][kk] = *(const short8*)(wp + kk * 32);
  }

  float c_reg[2][4], h_reg[2][4];
#pragma unroll
  for (int cg = 0; cg < 2; cg++) {
    const int j = wcols + cg * 16 + lr;
#pragma unroll
    for (int r = 0; r < 4; r++) {
      const int s = lq * 4 + r;
      float hv = hstate[(size_t)(b0 + s) * 256 + j];
      c_reg[cg][r] = cstate[(size_t)(b0 + s) * 256 + j];
      h_reg[cg][r] = hv;
      h_lds[s][j] = f2b(hv);
    }
  }
  __syncthreads();

  for (int blk = 0; blk < 10; blk += 4) {
    const int nst = (10 - blk) < 4 ? (10 - blk) : 4;
    // burst-stage nst steps of IH (nst x 32 KB) via global_load_lds
    for (int si = 0; si < nst; si++) {
      const ushort* src = IH + ((size_t)(blk + si) * 2048 + b0) * 1024;
#pragma unroll
      for (int u = 0; u < 4; u++) {
        const int bi = u * 8 + w;
        gload16(src + (size_t)bi * 512 + lane * 8, &ih_lds[si][bi * 512]);
      }
    }
    __syncthreads();   // stage drained; h_lds from prev step visible

    for (int i2 = 0; i2 < nst; i2++) {
      const int tl = blk + i2;
      const ushort* ihc = ih_lds[i2];
      // A fragments of h
      short8 af[8];
#pragma unroll
      for (int kk = 0; kk < 8; kk++)
        af[kk] = *(const short8*)(&h_lds[lr][kk * 32 + lq * 8]);
      __syncthreads();   // barrier-A: af reads done -> h_lds may be overwritten

      f32x4 acc[2][4];
#pragma unroll
      for (int cg = 0; cg < 2; cg++)
#pragma unroll
        for (int g = 0; g < 4; g++) acc[cg][g] = (f32x4){0.f, 0.f, 0.f, 0.f};

      // gate 0 (i): resident weights
#pragma unroll
      for (int cg = 0; cg < 2; cg++)
#pragma unroll
        for (int kk = 0; kk < 8; kk++)
          acc[cg][0] = __builtin_amdgcn_mfma_f32_16x16x32_bf16(
              af[kk], wres[cg][kk], acc[cg][0], 0, 0, 0);
      // gates 1..3 (f,g,o): streamed from (L2-resident) Whh
#pragma unroll
      for (int g = 1; g < 4; g++)
#pragma unroll
        for (int cg = 0; cg < 2; cg++) {
          const ushort* wp = Whh + (size_t)(g * 256 + wcols + cg * 16 + lr) * 256 + lq * 8;
          short8 wb[8];
#pragma unroll
          for (int kk = 0; kk < 8; kk++) wb[kk] = *(const short8*)(wp + kk * 32);
#pragma unroll
          for (int kk = 0; kk < 8; kk++)
            acc[cg][g] = __builtin_amdgcn_mfma_f32_16x16x32_bf16(
                af[kk], wb[kk], acc[cg][g], 0, 0, 0);
        }

      const int t = t0 + tl;
#pragma unroll
      for (int cg = 0; cg < 2; cg++) {
        const int j = wcols + cg * 16 + lr;
#pragma unroll
        for (int r = 0; r < 4; r++) {
          const int s = lq * 4 + r;
          const float zi = acc[cg][0][r] + b2f(ihc[s * 1024 + j]);
          const float zf = acc[cg][1][r] + b2f(ihc[s * 1024 + 256 + j]);
          const float zg = acc[cg][2][r] + b2f(ihc[s * 1024 + 512 + j]);
          const float zo = acc[cg][3][r] + b2f(ihc[s * 1024 + 768 + j]);
          const float ig = sigf(zi), fg = sigf(zf), gg = tanh_fast(zg), og = sigf(zo);
          const float c = fg * c_reg[cg][r] + ig * gg;
          c_reg[cg][r] = c;
          const float h = og * tanh_fast(c);
          h_reg[cg][r] = h;
          h_lds[s][j] = f2b(h);
          if (Hout) Hout[((size_t)t * 2048 + b0 + s) * 256 + j] = f2b(h);
          if (Xout)
            __builtin_nontemporal_store(h, &Xout[((size_t)(b0 + s) * 50 + t) * 256 + j]);
        }
      }
      __syncthreads();   // barrier-B: h visible before next step's af reads
    }
  }
#pragma unroll
  for (int cg = 0; cg < 2; cg++) {
    const int j = wcols + cg * 16 + lr;
#pragma unroll
    for (int r = 0; r < 4; r++) {
      const int s = lq * 4 + r;
      hstate[(size_t)(b0 + s) * 256 + j] = h_reg[cg][r];
      cstate[(size_t)(b0 + s) * 256 + j] = c_reg[cg][r];
    }
  }
}

// ---------------------------------------------------------------------------
__global__ void k_cffill(const float* __restrict__ hT, const ushort* __restrict__ recb,
                         ushort* __restrict__ cf) {
  long i = (long)blockIdx.x * blockDim.x + threadIdx.x;
  if (i < (long)2048 * 656) {
    long b = i / 656; int c = (int)(i % 656);
    cf[b * 704 + c] = (c < 256) ? f2b(hT[b * 256 + c]) : recb[b * 448 + (c - 256)];
  }
}

__global__ __launch_bounds__(256)
void k_cons(const float* __restrict__ c3, const float* __restrict__ w4,
            const float* __restrict__ b4, float* __restrict__ out) {
  __shared__ float red[256];
  float accv = 0.f;
  for (int b = threadIdx.x; b < 2048; b += 256) {
    float d = b4[0];
#pragma unroll
    for (int k = 0; k < 64; k++) d += c3[(long)b * 64 + k] * w4[k];
    accv += sigf(d);
  }
  red[threadIdx.x] = accv; __syncthreads();
  for (int s = 128; s > 0; s >>= 1) {
    if (threadIdx.x < s) red[threadIdx.x] += red[threadIdx.x + s];
    __syncthreads();
  }
  if (threadIdx.x == 0) out[0] = red[0] * (1.f / 2048.f);
}

__global__ __launch_bounds__(256)
void k_val(const float* __restrict__ x, float* __restrict__ out) {
  __shared__ float red[256];
  const float* p = x + (size_t)blockIdx.x * 12800;
  float a = 0.f;
  for (int i = threadIdx.x; i < 12800; i += 256) a += tanh_fast(p[i]);
  red[threadIdx.x] = a; __syncthreads();
  for (int s = 128; s > 0; s >>= 1) {
    if (threadIdx.x < s) red[threadIdx.x] += red[threadIdx.x + s];
    __syncthreads();
  }
  if (threadIdx.x == 0) out[blockIdx.x] = red[0] * (1.f / 12800.f);
}

// ---------------------------------------------------------------------------
// entanglement entropy: in-register unrolled 8x8 Jacobi
// ---------------------------------------------------------------------------
__global__ __launch_bounds__(64)
void k_ent(const float* __restrict__ ar, const float* __restrict__ ai,
           float* __restrict__ partial) {
  __shared__ float red[64];
  const int tid = threadIdx.x;
  const int b = blockIdx.x * 64 + tid;
  float vr[16], vi[16];
#pragma unroll
  for (int i = 0; i < 16; i++) { vr[i] = ar[b * 16 + i]; vi[i] = ai[b * 16 + i]; }
  float m[64];   // 8x8, compile-time indexed only -> registers
#pragma unroll
  for (int j = 0; j < 4; j++)
#pragma unroll
    for (int k = 0; k < 4; k++) {
      float re = 0.f, im = 0.f;
#pragma unroll
      for (int i = 0; i < 4; i++) {
        float xr = vr[i * 4 + j], xi = vi[i * 4 + j];
        float yr = vr[i * 4 + k], yi = vi[i * 4 + k];
        re += xr * yr + xi * yi;
        im += xi * yr - xr * yi;
      }
      m[j * 8 + k] = re;
      m[j * 8 + (k + 4)] = -im;
      m[(j + 4) * 8 + k] = im;
      m[(j + 4) * 8 + (k + 4)] = re;
    }
#pragma unroll 1
  for (int sweep = 0; sweep < 6; ++sweep) {
#pragma unroll
    for (int p = 0; p < 7; p++) {
#pragma unroll
      for (int q = p + 1; q < 8; q++) {
        const float apq = m[p * 8 + q];
        if (fabsf(apq) > 1e-28f) {
          const float app = m[p * 8 + p], aqq = m[q * 8 + q];
          const float tau = (aqq - app) / (2.f * apq);
          const float tt = (tau >= 0.f ? 1.f : -1.f) /
                           (fabsf(tau) + sqrtf(1.f + tau * tau));
          const float cc = 1.f / sqrtf(1.f + tt * tt);
          const float ssn = tt * cc;
#pragma unroll
          for (int k2 = 0; k2 < 8; k2++) {
            const float mp = m[p * 8 + k2], mq = m[q * 8 + k2];
            m[p * 8 + k2] = cc * mp - ssn * mq;
            m[q * 8 + k2] = ssn * mp + cc * mq;
          }
#pragma unroll
          for (int k2 = 0; k2 < 8; k2++) {
            const float mp = m[k2 * 8 + p], mq = m[k2 * 8 + q];
            m[k2 * 8 + p] = cc * mp - ssn * mq;
            m[k2 * 8 + q] = ssn * mp + cc * mq;
          }
        }
      }
    }
  }
  float e = 0.f;
#pragma unroll
  for (int k2 = 0; k2 < 8; k2++) {
    const float lam = fmaxf(m[k2 * 8 + k2], 1e-12f);
    e -= lam * logf(lam);
  }
  red[tid] = e; __syncthreads();
  for (int s = 32; s > 0; s >>= 1) {
    if (tid < s) red[tid] += red[tid + s];
    __syncthreads();
  }
  if (tid == 0) partial[blockIdx.x] = red[0];
}

__global__ void k_entfin(const float* __restrict__ partial, float* __restrict__ out) {
  if (threadIdx.x == 0) {
    float s = 0.f;
    for (int i = 0; i < 32; i++) s += partial[i];
    out[0] = s * (0.5f / 2048.f);
  }
}

// ---------------------------------------------------------------------------
extern "C" void kernel_launch(void* const* d_in, const int* in_sizes, int n_in,
                              void* d_out, int out_size, void* d_ws, size_t ws_size,
                              hipStream_t stream) {
  (void)in_sizes; (void)n_in; (void)out_size; (void)ws_size;
  const float* mf    = (const float*)d_in[0];
  const float* noise = (const float*)d_in[1];
  const float* ampr  = (const float*)d_in[2];
  const float* ampi  = (const float*)d_in[3];
  const float* Hre   = (const float*)d_in[4];
  const float* Him   = (const float*)d_in[5];
  const float* gpc   = (const float*)d_in[6];
  const float* bw1 = (const float*)d_in[7];  const float* bb1 = (const float*)d_in[8];
  const float* bw2 = (const float*)d_in[9];  const float* bb2 = (const float*)d_in[10];
  const float* bw3 = (const float*)d_in[11]; const float* bb3 = (const float*)d_in[12];
  const float* Wih[3] = {(const float*)d_in[13], (const float*)d_in[17], (const float*)d_in[21]};
  const float* Whh[3] = {(const float*)d_in[14], (const float*)d_in[18], (const float*)d_in[22]};
  const float* bih[3] = {(const float*)d_in[15], (const float*)d_in[19], (const float*)d_in[23]};
  const float* bhh[3] = {(const float*)d_in[16], (const float*)d_in[20], (const float*)d_in[24]};
  const float* cw1 = (const float*)d_in[25]; const float* cb1 = (const float*)d_in[26];
  const float* cw2 = (const float*)d_in[27]; const float* cb2 = (const float*)d_in[28];
  const float* cw3 = (const float*)d_in[29]; const float* cb3 = (const float*)d_in[30];
  const float* cw4 = (const float*)d_in[31]; const float* cb4 = (const float*)d_in[32];

  float* out = (float*)d_out;
  float* out_rec  = out;                    // [2048][400]
  float* out_seq  = out + 819200;           // [2048][50][256]
  float* out_val  = out + 27033600;         // [2048]
  float* out_cons = out + 27035648;
  float* out_ent  = out + 27035649;

  char* ws = (char*)d_ws;
  size_t off = 0;
  auto alloc = [&](size_t bytes) -> char* {
    char* p = ws + off; off += (bytes + 255) & ~(size_t)255; return p;
  };
  ushort* WB1   = (ushort*)alloc((size_t)256 * 576 * 2);
  ushort* WB2   = (ushort*)alloc((size_t)128 * 256 * 2);
  ushort* WB3   = (ushort*)alloc((size_t)512 * 128 * 2);
  ushort* WIH0  = (ushort*)alloc((size_t)1024 * 448 * 2);
  ushort* WIH0S = (ushort*)alloc((size_t)1024 * 448 * 2);
  ushort* WIH1  = (ushort*)alloc((size_t)1024 * 256 * 2);
  ushort* WIH2  = (ushort*)alloc((size_t)1024 * 256 * 2);
  ushort* WHH0  = (ushort*)alloc((size_t)1024 * 256 * 2);
  ushort* WHH1  = (ushort*)alloc((size_t)1024 * 256 * 2);
  ushort* WHH2  = (ushort*)alloc((size_t)1024 * 256 * 2);
  ushort* WC1   = (ushort*)alloc((size_t)512 * 704 * 2);
  ushort* WC2   = (ushort*)alloc((size_t)256 * 512 * 2);
  ushort* WC3   = (ushort*)alloc((size_t)128 * 256 * 2);
  float*  BSUM  = (float*)alloc((size_t)3 * 1024 * 4);
  ushort* BIO   = (ushort*)alloc((size_t)2048 * 576 * 2);
  ushort* H1B   = (ushort*)alloc((size_t)2048 * 256 * 2);
  ushort* H2B   = (ushort*)alloc((size_t)2048 * 128 * 2);
  ushort* RECB  = (ushort*)alloc((size_t)2048 * 448 * 2);
  float*  GG    = (float*)alloc((size_t)2048 * 1024 * 4);
  float*  AMPR  = (float*)alloc((size_t)2048 * 16 * 4);
  float*  AMPI  = (float*)alloc((size_t)2048 * 16 * 4);
  ushort* NCH   = (ushort*)alloc((size_t)10 * 2048 * 448 * 2);
  ushort* IHC   = (ushort*)alloc((size_t)10 * 2048 * 1024 * 2);
  ushort* HBUF  = (ushort*)alloc((size_t)50 * 2048 * 256 * 2);
  float*  HST   = (float*)alloc((size_t)2048 * 256 * 4);
  float*  CST   = (float*)alloc((size_t)2048 * 256 * 4);   // adjacent to HST
  ushort* CFB   = (ushort*)alloc((size_t)2048 * 704 * 2);
  ushort* C1B   = (ushort*)alloc((size_t)2048 * 512 * 2);
  ushort* C2B   = (ushort*)alloc((size_t)2048 * 256 * 2);
  float*  C3F   = (float*)alloc((size_t)2048 * 64 * 4);
  float*  ENTP  = (float*)alloc((size_t)32 * 4);

  hipMemsetAsync(BIO,  0, (size_t)2048 * 576 * 2, stream);
  hipMemsetAsync(RECB, 0, (size_t)2048 * 448 * 2, stream);
  hipMemsetAsync(CFB,  0, (size_t)2048 * 704 * 2, stream);

  auto convw = [&](const float* src, ushort* dst, int sr, int dr, int sc, int dc,
                   const float* scale, int mode) {
    long n = (long)dr * dc;
    int blocks = (int)((n + 255) / 256); if (blocks > 2048) blocks = 2048;
    hipLaunchKernelGGL(k_convw, dim3(blocks), dim3(256), 0, stream,
                       src, dst, sr, dr, sc, dc, scale, mode);
  };
  convw(bw1, WB1, 256, 256, 528, 576, nullptr, 0);
  convw(bw2, WB2, 128, 128, 256, 256, nullptr, 0);
  convw(bw3, WB3, 400, 512, 128, 128, nullptr, 0);
  convw(Wih[0], WIH0,  1024, 1024, 400, 448, nullptr, 0);
  convw(Wih[0], WIH0S, 1024, 1024, 400, 448, gpc, 1);   // fold sigmoid(gpc)
  convw(Wih[1], WIH1, 1024, 1024, 256, 256, nullptr, 0);
  convw(Wih[2], WIH2, 1024, 1024, 256, 256, nullptr, 0);
  convw(Whh[0], WHH0, 1024, 1024, 256, 256, nullptr, 0);
  convw(Whh[1], WHH1, 1024, 1024, 256, 256, nullptr, 0);
  convw(Whh[2], WHH2, 1024, 1024, 256, 256, nullptr, 0);
  convw(cw1, WC1, 512, 512, 656, 704, nullptr, 0);
  convw(cw2, WC2, 256, 256, 512, 512, nullptr, 0);
  convw(cw3, WC3,  64, 128, 256, 256, nullptr, 0);
  for (int l = 0; l < 3; l++)
    hipLaunchKernelGGL(k_vadd, dim3(4), dim3(256), 0, stream, bih[l], bhh[l], BSUM + l * 1024, 1024);

  hipLaunchKernelGGL(k_quantum, dim3(512), dim3(128), 0, stream,
                     ampr, ampi, Hre, Him, mf, BIO, AMPR, AMPI);
  hipLaunchKernelGGL(k_biofill, dim3(4096), dim3(256), 0, stream, mf, BIO);

  auto gemm = [&](bool big, const ushort* A, int lda, const ushort* W, int ldw,
                  const float* bias, const float* Gg, int t0, float* Cf, int ldcf,
                  ushort* Cb, int ldcb, int M, int N, int K, int act) {
    if (big) {
      dim3 grid((N + 127) / 128, M / 128);
      hipLaunchKernelGGL(k_gemm<128>, grid, dim3(256), 0, stream,
                         A, lda, W, ldw, bias, Gg, t0, Cf, ldcf, Cb, ldcb, N, K, act);
    } else {
      dim3 grid((N + 63) / 64, M / 64);
      hipLaunchKernelGGL(k_gemm<64>, grid, dim3(256), 0, stream,
                         A, lda, W, ldw, bias, Gg, t0, Cf, ldcf, Cb, ldcb, N, K, act);
    }
  };

  // receptor MLP
  gemm(false, BIO, 576, WB1, 576, bb1, nullptr, 0, nullptr, 0, H1B, 256, 2048, 256, 576, 1);
  gemm(false, H1B, 256, WB2, 256, bb2, nullptr, 0, nullptr, 0, H2B, 128, 2048, 128, 256, 2);
  gemm(false, H2B, 128, WB3, 128, bb3, nullptr, 0, out_rec, 400, RECB, 448, 2048, 400, 128, 3);
  // Gg = (receptor * sigmoid(gpc)) @ Wih0^T
  gemm(false, RECB, 448, WIH0S, 448, nullptr, nullptr, 0, GG, 1024, nullptr, 0, 2048, 1024, 448, 0);

  // 3-layer LSTM, chunked 10 timesteps
  for (int l = 0; l < 3; l++) {
    hipMemsetAsync(HST, 0, (size_t)2048 * 256 * 4 * 2, stream);   // HST + CST
    for (int c = 0; c < 5; c++) {
      int t0 = c * 10;
      if (l == 0) {
        hipLaunchKernelGGL(k_noiseconv, dim3(8192), dim3(256), 0, stream, noise, NCH, t0);
        gemm(true, NCH, 448, WIH0, 448, BSUM, GG, t0, nullptr, 0, IHC, 1024, 20480, 1024, 448, 0);
      } else {
        const ushort* Aip = HBUF + (size_t)t0 * 2048 * 256;
        gemm(true, Aip, 256, (l == 1 ? WIH1 : WIH2), 256, BSUM + l * 1024, nullptr, 0,
             nullptr, 0, IHC, 1024, 20480, 1024, 256, 0);
      }
      hipLaunchKernelGGL(k_rec, dim3(128), dim3(512), 0, stream,
                         IHC, (l == 0 ? WHH0 : l == 1 ? WHH1 : WHH2), HST, CST,
                         (l < 2 ? HBUF : (ushort*)nullptr),
                         (l == 2 ? out_seq : (float*)nullptr), t0);
    }
  }

  // consumer MLP
  hipLaunchKernelGGL(k_cffill, dim3(5256), dim3(256), 0, stream, HST, RECB, CFB);
  gemm(false, CFB, 704, WC1, 704, cb1, nullptr, 0, nullptr, 0, C1B, 512, 2048, 512, 704, 1);
  gemm(false, C1B, 512, WC2, 512, cb2, nullptr, 0, nullptr, 0, C2B, 256, 2048, 256, 512, 1);
  gemm(false, C2B, 256, WC3, 256, cb3, nullptr, 0, C3F, 64, nullptr, 0, 2048, 64, 256, 2);
  hipLaunchKernelGGL(k_cons, dim3(1), dim3(256), 0, stream, C3F, cw4, cb4, out_cons);

  // valence + entropy
  hipLaunchKernelGGL(k_val, dim3(2048), dim3(256), 0, stream, out_seq, out_val);
  hipLaunchKernelGGL(k_ent, dim3(32), dim3(64), 0, stream, AMPR, AMPI, ENTP);
  hipLaunchKernelGGL(k_entfin, dim3(1), dim3(32), 0, stream, ENTP, out_ent);
}

// Round 13
// 3354.357 us; speedup vs baseline: 1.3724x; 1.0003x over previous
//
#include <hip/hip_runtime.h>
#include <stdint.h>

// ---------------------------------------------------------------------------
// QuantumOlfactoryReceptor: full pipeline
// Round 13: base = R12 (3355us best).
//  (1) k_quantum -> 4 x 25-step launches (state via AMPR/AMPI) purely so the
//      top-5 profile reveals the true hotspot (everything hid under 184us).
//  (2) k_rec: streamed gates f,g,o software-pipelined with TWO named register
//      buffers (2-deep, manually unrolled) + gate-i resident MFMAs placed as
//      latency cover. Theory: single reused wb[] forced vmcnt-drain per batch
//      -> 6 x ~240cyc serial L2 latency per step.
// ---------------------------------------------------------------------------

using short8 = __attribute__((ext_vector_type(8))) short;
using f32x4  = __attribute__((ext_vector_type(4))) float;

#define DEV static __device__ __forceinline__

typedef const __attribute__((address_space(1))) void GV;
typedef __attribute__((address_space(3))) void LV;
DEV void gload16(const void* g, void* l) {
  __builtin_amdgcn_global_load_lds((GV*)g, (LV*)l, 16, 0, 0);
}

DEV ushort f2b(float x) {                       // f32 -> bf16 RNE
  union { float f; uint32_t u; } v; v.f = x;
  uint32_t r = v.u + 0x7FFFu + ((v.u >> 16) & 1u);
  return (ushort)(r >> 16);
}
DEV float b2f(ushort x) {
  union { uint32_t u; float f; } v; v.u = ((uint32_t)x) << 16; return v.f;
}
DEV float sigf(float x) { return 1.f / (1.f + __expf(-x)); }
DEV float tanh_fast(float x) {
  float xc = fminf(9.f, fmaxf(-9.f, x));
  float e = __expf(2.f * xc);
  return (e - 1.f) / (e + 1.f);
}

// ---------------------------------------------------------------------------
__global__ void k_convw(const float* __restrict__ src, ushort* __restrict__ dst,
                        int sr, int dr, int sc, int dc,
                        const float* __restrict__ scale, int mode) {
  long n = (long)dr * dc;
  for (long idx = (long)blockIdx.x * blockDim.x + threadIdx.x; idx < n;
       idx += (long)gridDim.x * blockDim.x) {
    int r = (int)(idx / dc), c = (int)(idx % dc);
    float v = 0.f;
    if (r < sr && c < sc) {
      v = src[(long)r * sc + c];
      if (mode == 1) v *= sigf(scale[c]);
    }
    dst[idx] = f2b(v);
  }
}

__global__ void k_vadd(const float* __restrict__ a, const float* __restrict__ b,
                       float* __restrict__ o, int n) {
  int i = blockIdx.x * blockDim.x + threadIdx.x;
  if (i < n) o[i] = a[i] + b[i];
}

// ---------------------------------------------------------------------------
// quantum evolution: 32 lanes per sample, Taylor action of expm, 6 terms.
// Runs steps [st0, st0+25); state in ampS_r/ampS_i. st0==0 normalizes inputs;
// bio written only when non-null (final chunk).
// ---------------------------------------------------------------------------
__global__ __launch_bounds__(128)
void k_quantum(const float* __restrict__ ampr_in, const float* __restrict__ ampi_in,
               const float* __restrict__ Hre, const float* __restrict__ Him,
               const float* __restrict__ mf,
               ushort* __restrict__ bio, float* __restrict__ ampS_r,
               float* __restrict__ ampS_i, int st0) {
  const int gid = blockIdx.x * 128 + threadIdx.x;
  const int b = gid >> 5;          // sample
  const int l32 = gid & 31;
  const int i = l32 & 15;          // row
  const int h = l32 >> 4;          // column half
  float hre[8], him[8];
#pragma unroll
  for (int jj = 0; jj < 8; jj++) {
    hre[jj] = Hre[i * 16 + h * 8 + jj];
    him[jj] = Him[i * 16 + h * 8 + jj];
  }
  const float mfi = mf[(long)b * 512 + i];
  float are, aim;
  if (st0 == 0) {
    are = ampr_in[b * 16 + i]; aim = ampi_in[b * 16 + i];
    float ss = are * are + aim * aim;
#pragma unroll
    for (int m = 1; m < 32; m <<= 1) ss += __shfl_xor(ss, m, 32);
    ss *= 0.5f;
    const float inv = 1.f / sqrtf(ss);
    are *= inv; aim *= inv;
  } else {
    are = ampS_r[b * 16 + i]; aim = ampS_i[b * 16 + i];
  }
#pragma unroll 1
  for (int st = st0; st < st0 + 25; ++st) {
    const float t = (float)st * 0.01f;
    const float fac = 1.f + t * mfi;
    const float dec = __expf(-t * 0.02f);   // exp(-t/50)
    float tre = are, tim = aim, rre = are, rim = aim;
#pragma unroll 1
    for (int k = 1; k <= 6; k++) {
      float w1r = 0.f, w1i = 0.f, w2r = 0.f, w2i = 0.f;
#pragma unroll
      for (int jj = 0; jj < 8; jj++) {
        const float vr = __shfl(tre, h * 8 + jj, 32);
        const float vi = __shfl(tim, h * 8 + jj, 32);
        w1r += hre[jj] * vr; w1i += hre[jj] * vi;
        w2r += him[jj] * vr; w2i += him[jj] * vi;
      }
      w1r += __shfl_xor(w1r, 16, 32);
      w1i += __shfl_xor(w1i, 16, 32);
      w2r += __shfl_xor(w2r, 16, 32);
      w2i += __shfl_xor(w2i, 16, 32);
      const float hr = w1r * fac - w2i;      // (Ht v)_re
      const float hi = w1i * fac + w2r;      // (Ht v)_im
      const float sk = 0.01f / (float)k;     // DT/k ; term *= -i*sk
      tre = sk * hi; tim = -sk * hr;
      rre += tre; rim += tim;
    }
    are = rre * dec; aim = rim * dec;
  }
  if (h == 0) {
    ampS_r[b * 16 + i] = are;
    ampS_i[b * 16 + i] = aim;
    if (bio) bio[(long)b * 576 + i] = f2b(are * are + aim * aim);   // obs
  }
}

__global__ void k_biofill(const float* __restrict__ mf, ushort* __restrict__ bio) {
  long i = (long)blockIdx.x * blockDim.x + threadIdx.x;
  if (i < (long)2048 * 512) {
    long b = i >> 9, k = i & 511;
    bio[b * 576 + 16 + k] = f2b(mf[i]);
  }
}

// ---------------------------------------------------------------------------
// m97-structure bf16 MFMA GEMM (cached C-writes)
// ---------------------------------------------------------------------------
template<int BT>
__global__ __launch_bounds__(256)
void k_gemm(const ushort* __restrict__ A, int lda,
            const ushort* __restrict__ W, int ldw,
            const float* __restrict__ bias,
            const float* __restrict__ Gg, int t0,
            float* __restrict__ Cf, int ldcf,
            ushort* __restrict__ Cb, int ldcb,
            int N, int K, int act) {
  constexpr int FR = BT / 32;
  constexpr int CH = BT / 32;
  __shared__ __align__(16) ushort lsA[BT * 64];
  __shared__ __align__(16) ushort lsB[BT * 64];
  const int tid = threadIdx.x;
  const int lane = tid & 63, w = tid >> 6;
  const int lr = lane & 15, lq = lane >> 4;
  const int wm = (w >> 1) * (BT / 2), wn = (w & 1) * (BT / 2);
  const int bm = blockIdx.y * BT, bn = blockIdx.x * BT;
  const int srow = lane >> 3;
  const int scol = (lane & 7) * 8;

  f32x4 acc[FR][FR];
#pragma unroll
  for (int i = 0; i < FR; i++)
#pragma unroll
    for (int j = 0; j < FR; j++) acc[i][j] = (f32x4){0.f, 0.f, 0.f, 0.f};

  for (int kk = 0; kk < K; kk += 64) {
#pragma unroll
    for (int c = 0; c < CH; c++) {
      const int ch = w * CH + c;
      const int r = ch * 8 + srow;
      gload16(A + (size_t)(bm + r) * lda + kk + scol, lsA + ch * 512);
      gload16(W + (size_t)(bn + r) * ldw + kk + scol, lsB + ch * 512);
    }
    __syncthreads();
    short8 af[FR][2], bf[FR][2];
#pragma unroll
    for (int mi = 0; mi < FR; mi++)
#pragma unroll
      for (int k2 = 0; k2 < 2; k2++)
        af[mi][k2] = *(const short8*)(lsA + (wm + mi * 16 + lr) * 64 + k2 * 32 + lq * 8);
#pragma unroll
    for (int ni = 0; ni < FR; ni++)
#pragma unroll
      for (int k2 = 0; k2 < 2; k2++)
        bf[ni][k2] = *(const short8*)(lsB + (wn + ni * 16 + lr) * 64 + k2 * 32 + lq * 8);
#pragma unroll
    for (int k2 = 0; k2 < 2; k2++)
#pragma unroll
      for (int mi = 0; mi < FR; mi++)
#pragma unroll
        for (int ni = 0; ni < FR; ni++)
          acc[mi][ni] = __builtin_amdgcn_mfma_f32_16x16x32_bf16(
              af[mi][k2], bf[ni][k2], acc[mi][ni], 0, 0, 0);
    __syncthreads();
  }

#pragma unroll
  for (int mi = 0; mi < FR; mi++) {
#pragma unroll
    for (int r = 0; r < 4; r++) {
      const int row = bm + wm + mi * 16 + lq * 4 + r;
      float gfac = 0.f; const float* ggrow = nullptr;
      if (Gg) {
        gfac = __expf(-(float)(t0 + (row >> 11)) * 0.1f);   // adapt(t)
        ggrow = Gg + (size_t)(row & 2047) * 1024;
      }
#pragma unroll
      for (int ni = 0; ni < FR; ni++) {
        const int col = bn + wn + ni * 16 + lr;
        if (col < N) {
          float v = acc[mi][ni][r];
          if (bias) v += bias[col];
          if (Gg)  v += gfac * ggrow[col];
          if (act == 1) v = fmaxf(v, 0.f);
          else if (act == 2) v = tanh_fast(v);
          else if (act == 3) v = sigf(v);
          if (Cf) Cf[(size_t)row * ldcf + col] = v;
          if (Cb) Cb[(size_t)row * ldcb + col] = f2b(v);
        }
      }
    }
  }
}

// ---------------------------------------------------------------------------
__global__ void k_noiseconv(const float* __restrict__ noise, ushort* __restrict__ dst, int t0) {
  long n = 10L * 2048 * 448;
  for (long idx = (long)blockIdx.x * blockDim.x + threadIdx.x; idx < n;
       idx += (long)gridDim.x * blockDim.x) {
    int r = (int)(idx % 448);
    long row = idx / 448;
    int b = (int)(row & 2047);
    int tl = (int)(row >> 11);
    ushort v = 0;
    if (r < 400)
      v = f2b(__builtin_nontemporal_load(&noise[((long)b * 50 + t0 + tl) * 400 + r]));
    dst[idx] = v;
  }
}

// ---------------------------------------------------------------------------
// LSTM recurrence, 10 timesteps/launch. 128 WGs x 16 samples x 8 waves.
// R12 block-staged IH (4-step 128KB bursts) + R13 pipelined weight stream:
// gates f,g,o loaded through TWO named register buffers (2-deep dbuf,
// manually unrolled), gate-i resident MFMAs placed as latency cover.
// ---------------------------------------------------------------------------
__global__ __launch_bounds__(512, 2)
void k_rec(const ushort* __restrict__ IH, const ushort* __restrict__ Whh,
           float* __restrict__ hstate, float* __restrict__ cstate,
           ushort* __restrict__ Hout, float* __restrict__ Xout, int t0) {
  __shared__ ushort h_lds[16][266];                      // odd dword stride
  __shared__ __align__(16) ushort ih_lds[4][16 * 1024];  // 4-step block, 128 KB
  const int tid = threadIdx.x;
  const int lane = tid & 63, w = tid >> 6;               // w in [0,8)
  const int lr = lane & 15, lq = lane >> 4;
  const int b0 = blockIdx.x * 16;
  const int wcols = w * 32;

  // resident gate-i weights: 2 col-groups x 8 k-chunks = 64 VGPRs
  short8 wres[2][8];
#pragma unroll
  for (int cg = 0; cg < 2; cg++) {
    const ushort* wp = Whh + (size_t)(wcols + cg * 16 + lr) * 256 + lq * 8;
#pragma unroll
    for (int kk = 0; kk < 8; kk++) wres[cg][kk] = *(const short8*)(wp + kk * 32);
  }

  float c_reg[2][4], h_reg[2][4];
#pragma unroll
  for (int cg = 0; cg < 2; cg++) {
    const int j = wcols + cg * 16 + lr;
#pragma unroll
    for (int r = 0; r < 4; r++) {
      const int s = lq * 4 + r;
      float hv = hstate[(size_t)(b0 + s) * 256 + j];
      c_reg[cg][r] = cstate[(size_t)(b0 + s) * 256 + j];
      h_reg[cg][r] = hv;
      h_lds[s][j] = f2b(hv);
    }
  }
  __syncthreads();

#define LOADB(buf, g, cg) { \
  const ushort* wp_ = Whh + (size_t)((g) * 256 + wcols + (cg) * 16 + lr) * 256 + lq * 8; \
  _Pragma("unroll") for (int kk = 0; kk < 8; kk++) (buf)[kk] = *(const short8*)(wp_ + kk * 32); }
#define MFMAB(buf, g, cg) { \
  _Pragma("unroll") for (int kk = 0; kk < 8; kk++) \
    acc[cg][g] = __builtin_amdgcn_mfma_f32_16x16x32_bf16(af[kk], (buf)[kk], acc[cg][g], 0, 0, 0); }
#define MFMAR(cg) { \
  _Pragma("unroll") for (int kk = 0; kk < 8; kk++) \
    acc[cg][0] = __builtin_amdgcn_mfma_f32_16x16x32_bf16(af[kk], wres[cg][kk], acc[cg][0], 0, 0, 0); }

  for (int blk = 0; blk < 10; blk += 4) {
    const int nst = (10 - blk) < 4 ? (10 - blk) : 4;
    // burst-stage nst steps of IH (nst x 32 KB) via global_load_lds
    for (int si = 0; si < nst; si++) {
      const ushort* src = IH + ((size_t)(blk + si) * 2048 + b0) * 1024;
#pragma unroll
      for (int u = 0; u < 4; u++) {
        const int bi = u * 8 + w;
        gload16(src + (size_t)bi * 512 + lane * 8, &ih_lds[si][bi * 512]);
      }
    }
    __syncthreads();   // stage drained; h_lds from prev step visible

    for (int i2 = 0; i2 < nst; i2++) {
      const int tl = blk + i2;
      const ushort* ihc = ih_lds[i2];
      // A fragments of h
      short8 af[8];
#pragma unroll
      for (int kk = 0; kk < 8; kk++)
        af[kk] = *(const short8*)(&h_lds[lr][kk * 32 + lq * 8]);
      __syncthreads();   // barrier-A: af reads done -> h_lds may be overwritten

      f32x4 acc[2][4];
#pragma unroll
      for (int cg = 0; cg < 2; cg++)
#pragma unroll
        for (int g = 0; g < 4; g++) acc[cg][g] = (f32x4){0.f, 0.f, 0.f, 0.f};

      // pipelined weight stream: 2-deep register dbuf, gate-i as latency cover
      short8 wb0[8], wb1[8];
      LOADB(wb0, 1, 0);
      LOADB(wb1, 1, 1);
      MFMAR(0);            // resident gate-i col-group 0 (no loads)
      MFMAR(1);            // resident gate-i col-group 1
      MFMAB(wb0, 1, 0);
      LOADB(wb0, 2, 0);
      MFMAB(wb1, 1, 1);
      LOADB(wb1, 2, 1);
      MFMAB(wb0, 2, 0);
      LOADB(wb0, 3, 0);
      MFMAB(wb1, 2, 1);
      LOADB(wb1, 3, 1);
      MFMAB(wb0, 3, 0);
      MFMAB(wb1, 3, 1);

      const int t = t0 + tl;
#pragma unroll
      for (int cg = 0; cg < 2; cg++) {
        const int j = wcols + cg * 16 + lr;
#pragma unroll
        for (int r = 0; r < 4; r++) {
          const int s = lq * 4 + r;
          const float zi = acc[cg][0][r] + b2f(ihc[s * 1024 + j]);
          const float zf = acc[cg][1][r] + b2f(ihc[s * 1024 + 256 + j]);
          const float zg = acc[cg][2][r] + b2f(ihc[s * 1024 + 512 + j]);
          const float zo = acc[cg][3][r] + b2f(ihc[s * 1024 + 768 + j]);
          const float ig = sigf(zi), fg = sigf(zf), gg = tanh_fast(zg), og = sigf(zo);
          const float c = fg * c_reg[cg][r] + ig * gg;
          c_reg[cg][r] = c;
          const float h = og * tanh_fast(c);
          h_reg[cg][r] = h;
          h_lds[s][j] = f2b(h);
          if (Hout) Hout[((size_t)t * 2048 + b0 + s) * 256 + j] = f2b(h);
          if (Xout)
            __builtin_nontemporal_store(h, &Xout[((size_t)(b0 + s) * 50 + t) * 256 + j]);
        }
      }
      __syncthreads();   // barrier-B: h visible before next step's af reads
    }
  }
#undef LOADB
#undef MFMAB
#undef MFMAR
#pragma unroll
  for (int cg = 0; cg < 2; cg++) {
    const int j = wcols + cg * 16 + lr;
#pragma unroll
    for (int r = 0; r < 4; r++) {
      const int s = lq * 4 + r;
      hstate[(size_t)(b0 + s) * 256 + j] = h_reg[cg][r];
      cstate[(size_t)(b0 + s) * 256 + j] = c_reg[cg][r];
    }
  }
}

// ---------------------------------------------------------------------------
__global__ void k_cffill(const float* __restrict__ hT, const ushort* __restrict__ recb,
                         ushort* __restrict__ cf) {
  long i = (long)blockIdx.x * blockDim.x + threadIdx.x;
  if (i < (long)2048 * 656) {
    long b = i / 656; int c = (int)(i % 656);
    cf[b * 704 + c] = (c < 256) ? f2b(hT[b * 256 + c]) : recb[b * 448 + (c - 256)];
  }
}

__global__ __launch_bounds__(256)
void k_cons(const float* __restrict__ c3, const float* __restrict__ w4,
            const float* __restrict__ b4, float* __restrict__ out) {
  __shared__ float red[256];
  float accv = 0.f;
  for (int b = threadIdx.x; b < 2048; b += 256) {
    float d = b4[0];
#pragma unroll
    for (int k = 0; k < 64; k++) d += c3[(long)b * 64 + k] * w4[k];
    accv += sigf(d);
  }
  red[threadIdx.x] = accv; __syncthreads();
  for (int s = 128; s > 0; s >>= 1) {
    if (threadIdx.x < s) red[threadIdx.x] += red[threadIdx.x + s];
    __syncthreads();
  }
  if (threadIdx.x == 0) out[0] = red[0] * (1.f / 2048.f);
}

__global__ __launch_bounds__(256)
void k_val(const float* __restrict__ x, float* __restrict__ out) {
  __shared__ float red[256];
  const float* p = x + (size_t)blockIdx.x * 12800;
  float a = 0.f;
  for (int i = threadIdx.x; i < 12800; i += 256) a += tanh_fast(p[i]);
  red[threadIdx.x] = a; __syncthreads();
  for (int s = 128; s > 0; s >>= 1) {
    if (threadIdx.x < s) red[threadIdx.x] += red[threadIdx.x + s];
    __syncthreads();
  }
  if (threadIdx.x == 0) out[blockIdx.x] = red[0] * (1.f / 12800.f);
}

// ---------------------------------------------------------------------------
// entanglement entropy: in-register unrolled 8x8 Jacobi
// ---------------------------------------------------------------------------
__global__ __launch_bounds__(64)
void k_ent(const float* __restrict__ ar, const float* __restrict__ ai,
           float* __restrict__ partial) {
  __shared__ float red[64];
  const int tid = threadIdx.x;
  const int b = blockIdx.x * 64 + tid;
  float vr[16], vi[16];
#pragma unroll
  for (int i = 0; i < 16; i++) { vr[i] = ar[b * 16 + i]; vi[i] = ai[b * 16 + i]; }
  float m[64];   // 8x8, compile-time indexed only -> registers
#pragma unroll
  for (int j = 0; j < 4; j++)
#pragma unroll
    for (int k = 0; k < 4; k++) {
      float re = 0.f, im = 0.f;
#pragma unroll
      for (int i = 0; i < 4; i++) {
        float xr = vr[i * 4 + j], xi = vi[i * 4 + j];
        float yr = vr[i * 4 + k], yi = vi[i * 4 + k];
        re += xr * yr + xi * yi;
        im += xi * yr - xr * yi;
      }
      m[j * 8 + k] = re;
      m[j * 8 + (k + 4)] = -im;
      m[(j + 4) * 8 + k] = im;
      m[(j + 4) * 8 + (k + 4)] = re;
    }
#pragma unroll 1
  for (int sweep = 0; sweep < 6; ++sweep) {
#pragma unroll
    for (int p = 0; p < 7; p++) {
#pragma unroll
      for (int q = p + 1; q < 8; q++) {
        const float apq = m[p * 8 + q];
        if (fabsf(apq) > 1e-28f) {
          const float app = m[p * 8 + p], aqq = m[q * 8 + q];
          const float tau = (aqq - app) / (2.f * apq);
          const float tt = (tau >= 0.f ? 1.f : -1.f) /
                           (fabsf(tau) + sqrtf(1.f + tau * tau));
          const float cc = 1.f / sqrtf(1.f + tt * tt);
          const float ssn = tt * cc;
#pragma unroll
          for (int k2 = 0; k2 < 8; k2++) {
            const float mp = m[p * 8 + k2], mq = m[q * 8 + k2];
            m[p * 8 + k2] = cc * mp - ssn * mq;
            m[q * 8 + k2] = ssn * mp + cc * mq;
          }
#pragma unroll
          for (int k2 = 0; k2 < 8; k2++) {
            const float mp = m[k2 * 8 + p], mq = m[k2 * 8 + q];
            m[k2 * 8 + p] = cc * mp - ssn * mq;
            m[k2 * 8 + q] = ssn * mp + cc * mq;
          }
        }
      }
    }
  }
  float e = 0.f;
#pragma unroll
  for (int k2 = 0; k2 < 8; k2++) {
    const float lam = fmaxf(m[k2 * 8 + k2], 1e-12f);
    e -= lam * logf(lam);
  }
  red[tid] = e; __syncthreads();
  for (int s = 32; s > 0; s >>= 1) {
    if (tid < s) red[tid] += red[tid + s];
    __syncthreads();
  }
  if (tid == 0) partial[blockIdx.x] = red[0];
}

__global__ void k_entfin(const float* __restrict__ partial, float* __restrict__ out) {
  if (threadIdx.x == 0) {
    float s = 0.f;
    for (int i = 0; i < 32; i++) s += partial[i];
    out[0] = s * (0.5f / 2048.f);
  }
}

// ---------------------------------------------------------------------------
extern "C" void kernel_launch(void* const* d_in, const int* in_sizes, int n_in,
                              void* d_out, int out_size, void* d_ws, size_t ws_size,
                              hipStream_t stream) {
  (void)in_sizes; (void)n_in; (void)out_size; (void)ws_size;
  const float* mf    = (const float*)d_in[0];
  const float* noise = (const float*)d_in[1];
  const float* ampr  = (const float*)d_in[2];
  const float* ampi  = (const float*)d_in[3];
  const float* Hre   = (const float*)d_in[4];
  const float* Him   = (const float*)d_in[5];
  const float* gpc   = (const float*)d_in[6];
  const float* bw1 = (const float*)d_in[7];  const float* bb1 = (const float*)d_in[8];
  const float* bw2 = (const float*)d_in[9];  const float* bb2 = (const float*)d_in[10];
  const float* bw3 = (const float*)d_in[11]; const float* bb3 = (const float*)d_in[12];
  const float* Wih[3] = {(const float*)d_in[13], (const float*)d_in[17], (const float*)d_in[21]};
  const float* Whh[3] = {(const float*)d_in[14], (const float*)d_in[18], (const float*)d_in[22]};
  const float* bih[3] = {(const float*)d_in[15], (const float*)d_in[19], (const float*)d_in[23]};
  const float* bhh[3] = {(const float*)d_in[16], (const float*)d_in[20], (const float*)d_in[24]};
  const float* cw1 = (const float*)d_in[25]; const float* cb1 = (const float*)d_in[26];
  const float* cw2 = (const float*)d_in[27]; const float* cb2 = (const float*)d_in[28];
  const float* cw3 = (const float*)d_in[29]; const float* cb3 = (const float*)d_in[30];
  const float* cw4 = (const float*)d_in[31]; const float* cb4 = (const float*)d_in[32];

  float* out = (float*)d_out;
  float* out_rec  = out;                    // [2048][400]
  float* out_seq  = out + 819200;           // [2048][50][256]
  float* out_val  = out + 27033600;         // [2048]
  float* out_cons = out + 27035648;
  float* out_ent  = out + 27035649;

  char* ws = (char*)d_ws;
  size_t off = 0;
  auto alloc = [&](size_t bytes) -> char* {
    char* p = ws + off; off += (bytes + 255) & ~(size_t)255; return p;
  };
  ushort* WB1   = (ushort*)alloc((size_t)256 * 576 * 2);
  ushort* WB2   = (ushort*)alloc((size_t)128 * 256 * 2);
  ushort* WB3   = (ushort*)alloc((size_t)512 * 128 * 2);
  ushort* WIH0  = (ushort*)alloc((size_t)1024 * 448 * 2);
  ushort* WIH0S = (ushort*)alloc((size_t)1024 * 448 * 2);
  ushort* WIH1  = (ushort*)alloc((size_t)1024 * 256 * 2);
  ushort* WIH2  = (ushort*)alloc((size_t)1024 * 256 * 2);
  ushort* WHH0  = (ushort*)alloc((size_t)1024 * 256 * 2);
  ushort* WHH1  = (ushort*)alloc((size_t)1024 * 256 * 2);
  ushort* WHH2  = (ushort*)alloc((size_t)1024 * 256 * 2);
  ushort* WC1   = (ushort*)alloc((size_t)512 * 704 * 2);
  ushort* WC2   = (ushort*)alloc((size_t)256 * 512 * 2);
  ushort* WC3   = (ushort*)alloc((size_t)128 * 256 * 2);
  float*  BSUM  = (float*)alloc((size_t)3 * 1024 * 4);
  ushort* BIO   = (ushort*)alloc((size_t)2048 * 576 * 2);
  ushort* H1B   = (ushort*)alloc((size_t)2048 * 256 * 2);
  ushort* H2B   = (ushort*)alloc((size_t)2048 * 128 * 2);
  ushort* RECB  = (ushort*)alloc((size_t)2048 * 448 * 2);
  float*  GG    = (float*)alloc((size_t)2048 * 1024 * 4);
  float*  AMPR  = (float*)alloc((size_t)2048 * 16 * 4);
  float*  AMPI  = (float*)alloc((size_t)2048 * 16 * 4);
  ushort* NCH   = (ushort*)alloc((size_t)10 * 2048 * 448 * 2);
  ushort* IHC   = (ushort*)alloc((size_t)10 * 2048 * 1024 * 2);
  ushort* HBUF  = (ushort*)alloc((size_t)50 * 2048 * 256 * 2);
  float*  HST   = (float*)alloc((size_t)2048 * 256 * 4);
  float*  CST   = (float*)alloc((size_t)2048 * 256 * 4);   // adjacent to HST
  ushort* CFB   = (ushort*)alloc((size_t)2048 * 704 * 2);
  ushort* C1B   = (ushort*)alloc((size_t)2048 * 512 * 2);
  ushort* C2B   = (ushort*)alloc((size_t)2048 * 256 * 2);
  float*  C3F   = (float*)alloc((size_t)2048 * 64 * 4);
  float*  ENTP  = (float*)alloc((size_t)32 * 4);

  hipMemsetAsync(BIO,  0, (size_t)2048 * 576 * 2, stream);
  hipMemsetAsync(RECB, 0, (size_t)2048 * 448 * 2, stream);
  hipMemsetAsync(CFB,  0, (size_t)2048 * 704 * 2, stream);

  auto convw = [&](const float* src, ushort* dst, int sr, int dr, int sc, int dc,
                   const float* scale, int mode) {
    long n = (long)dr * dc;
    int blocks = (int)((n + 255) / 256); if (blocks > 2048) blocks = 2048;
    hipLaunchKernelGGL(k_convw, dim3(blocks), dim3(256), 0, stream,
                       src, dst, sr, dr, sc, dc, scale, mode);
  };
  convw(bw1, WB1, 256, 256, 528, 576, nullptr, 0);
  convw(bw2, WB2, 128, 128, 256, 256, nullptr, 0);
  convw(bw3, WB3, 400, 512, 128, 128, nullptr, 0);
  convw(Wih[0], WIH0,  1024, 1024, 400, 448, nullptr, 0);
  convw(Wih[0], WIH0S, 1024, 1024, 400, 448, gpc, 1);   // fold sigmoid(gpc)
  convw(Wih[1], WIH1, 1024, 1024, 256, 256, nullptr, 0);
  convw(Wih[2], WIH2, 1024, 1024, 256, 256, nullptr, 0);
  convw(Whh[0], WHH0, 1024, 1024, 256, 256, nullptr, 0);
  convw(Whh[1], WHH1, 1024, 1024, 256, 256, nullptr, 0);
  convw(Whh[2], WHH2, 1024, 1024, 256, 256, nullptr, 0);
  convw(cw1, WC1, 512, 512, 656, 704, nullptr, 0);
  convw(cw2, WC2, 256, 256, 512, 512, nullptr, 0);
  convw(cw3, WC3,  64, 128, 256, 256, nullptr, 0);
  for (int l = 0; l < 3; l++)
    hipLaunchKernelGGL(k_vadd, dim3(4), dim3(256), 0, stream, bih[l], bhh[l], BSUM + l * 1024, 1024);

  // quantum: four 25-step chunks (diagnostic split; state via AMPR/AMPI)
  for (int qc = 0; qc < 4; qc++)
    hipLaunchKernelGGL(k_quantum, dim3(512), dim3(128), 0, stream,
                       ampr, ampi, Hre, Him, mf,
                       (qc == 3 ? BIO : (ushort*)nullptr), AMPR, AMPI, qc * 25);
  hipLaunchKernelGGL(k_biofill, dim3(4096), dim3(256), 0, stream, mf, BIO);

  auto gemm = [&](bool big, const ushort* A, int lda, const ushort* W, int ldw,
                  const float* bias, const float* Gg, int t0, float* Cf, int ldcf,
                  ushort* Cb, int ldcb, int M, int N, int K, int act) {
    if (big) {
      dim3 grid((N + 127) / 128, M / 128);
      hipLaunchKernelGGL(k_gemm<128>, grid, dim3(256), 0, stream,
                         A, lda, W, ldw, bias, Gg, t0, Cf, ldcf, Cb, ldcb, N, K, act);
    } else {
      dim3 grid((N + 63) / 64, M / 64);
      hipLaunchKernelGGL(k_gemm<64>, grid, dim3(256), 0, stream,
                         A, lda, W, ldw, bias, Gg, t0, Cf, ldcf, Cb, ldcb, N, K, act);
    }
  };

  // receptor MLP
  gemm(false, BIO, 576, WB1, 576, bb1, nullptr, 0, nullptr, 0, H1B, 256, 2048, 256, 576, 1);
  gemm(false, H1B, 256, WB2, 256, bb2, nullptr, 0, nullptr, 0, H2B, 128, 2048, 128, 256, 2);
  gemm(false, H2B, 128, WB3, 128, bb3, nullptr, 0, out_rec, 400, RECB, 448, 2048, 400, 128, 3);
  // Gg = (receptor * sigmoid(gpc)) @ Wih0^T
  gemm(false, RECB, 448, WIH0S, 448, nullptr, nullptr, 0, GG, 1024, nullptr, 0, 2048, 1024, 448, 0);

  // 3-layer LSTM, chunked 10 timesteps
  for (int l = 0; l < 3; l++) {
    hipMemsetAsync(HST, 0, (size_t)2048 * 256 * 4 * 2, stream);   // HST + CST
    for (int c = 0; c < 5; c++) {
      int t0 = c * 10;
      if (l == 0) {
        hipLaunchKernelGGL(k_noiseconv, dim3(8192), dim3(256), 0, stream, noise, NCH, t0);
        gemm(true, NCH, 448, WIH0, 448, BSUM, GG, t0, nullptr, 0, IHC, 1024, 20480, 1024, 448, 0);
      } else {
        const ushort* Aip = HBUF + (size_t)t0 * 2048 * 256;
        gemm(true, Aip, 256, (l == 1 ? WIH1 : WIH2), 256, BSUM + l * 1024, nullptr, 0,
             nullptr, 0, IHC, 1024, 20480, 1024, 256, 0);
      }
      hipLaunchKernelGGL(k_rec, dim3(128), dim3(512), 0, stream,
                         IHC, (l == 0 ? WHH0 : l == 1 ? WHH1 : WHH2), HST, CST,
                         (l < 2 ? HBUF : (ushort*)nullptr),
                         (l == 2 ? out_seq : (float*)nullptr), t0);
    }
  }

  // consumer MLP
  hipLaunchKernelGGL(k_cffill, dim3(5256), dim3(256), 0, stream, HST, RECB, CFB);
  gemm(false, CFB, 704, WC1, 704, cb1, nullptr, 0, nullptr, 0, C1B, 512, 2048, 512, 704, 1);
  gemm(false, C1B, 512, WC2, 512, cb2, nullptr, 0, nullptr, 0, C2B, 256, 2048, 256, 512, 1);
  gemm(false, C2B, 256, WC3, 256, cb3, nullptr, 0, C3F, 64, nullptr, 0, 2048, 64, 256, 2);
  hipLaunchKernelGGL(k_cons, dim3(1), dim3(256), 0, stream, C3F, cw4, cb4, out_cons);

  // valence + entropy
  hipLaunchKernelGGL(k_val, dim3(2048), dim3(256), 0, stream, out_seq, out_val);
  hipLaunchKernelGGL(k_ent, dim3(32), dim3(64), 0, stream, AMPR, AMPI, ENTP);
  hipLaunchKernelGGL(k_entfin, dim3(1), dim3(32), 0, stream, ENTP, out_ent);
}

// Round 14
// 3328.996 us; speedup vs baseline: 1.3829x; 1.0076x over previous
//
#include <hip/hip_runtime.h>
#include <stdint.h>

// ---------------------------------------------------------------------------
// QuantumOlfactoryReceptor: full pipeline
// Round 14: base = R13 (3354us). k_gemm attack (profile: 15 x 118us, the
//  dominant cost):
//  (1) XCD-aware grid remap for the big (8 x 160) GEMMs: each XCD owns a
//      contiguous bm-slice (20 row-blocks x all bn) -> per-XCD A footprint
//      2.3MB < 4MB L2 -> FETCH 85.6 -> ~30MB (was 8x A over-fetch because
//      XCD==bn meant every XCD streamed ALL of A).
//  (2) LDS XOR-swizzle (pre-swizzled global source + swizzled ds_read,
//      gload_lds dest linear): kills the 6.9M 8-way bank conflicts on the
//      stride-128B fragment reads.
// ---------------------------------------------------------------------------

using short8 = __attribute__((ext_vector_type(8))) short;
using f32x4  = __attribute__((ext_vector_type(4))) float;

#define DEV static __device__ __forceinline__

typedef const __attribute__((address_space(1))) void GV;
typedef __attribute__((address_space(3))) void LV;
DEV void gload16(const void* g, void* l) {
  __builtin_amdgcn_global_load_lds((GV*)g, (LV*)l, 16, 0, 0);
}

DEV ushort f2b(float x) {                       // f32 -> bf16 RNE
  union { float f; uint32_t u; } v; v.f = x;
  uint32_t r = v.u + 0x7FFFu + ((v.u >> 16) & 1u);
  return (ushort)(r >> 16);
}
DEV float b2f(ushort x) {
  union { uint32_t u; float f; } v; v.u = ((uint32_t)x) << 16; return v.f;
}
DEV float sigf(float x) { return 1.f / (1.f + __expf(-x)); }
DEV float tanh_fast(float x) {
  float xc = fminf(9.f, fmaxf(-9.f, x));
  float e = __expf(2.f * xc);
  return (e - 1.f) / (e + 1.f);
}

// ---------------------------------------------------------------------------
__global__ void k_convw(const float* __restrict__ src, ushort* __restrict__ dst,
                        int sr, int dr, int sc, int dc,
                        const float* __restrict__ scale, int mode) {
  long n = (long)dr * dc;
  for (long idx = (long)blockIdx.x * blockDim.x + threadIdx.x; idx < n;
       idx += (long)gridDim.x * blockDim.x) {
    int r = (int)(idx / dc), c = (int)(idx % dc);
    float v = 0.f;
    if (r < sr && c < sc) {
      v = src[(long)r * sc + c];
      if (mode == 1) v *= sigf(scale[c]);
    }
    dst[idx] = f2b(v);
  }
}

__global__ void k_vadd(const float* __restrict__ a, const float* __restrict__ b,
                       float* __restrict__ o, int n) {
  int i = blockIdx.x * blockDim.x + threadIdx.x;
  if (i < n) o[i] = a[i] + b[i];
}

// ---------------------------------------------------------------------------
// quantum evolution: 32 lanes per sample, Taylor action of expm, 6 terms.
// Runs steps [st0, st0+25); state in ampS_r/ampS_i.
// ---------------------------------------------------------------------------
__global__ __launch_bounds__(128)
void k_quantum(const float* __restrict__ ampr_in, const float* __restrict__ ampi_in,
               const float* __restrict__ Hre, const float* __restrict__ Him,
               const float* __restrict__ mf,
               ushort* __restrict__ bio, float* __restrict__ ampS_r,
               float* __restrict__ ampS_i, int st0) {
  const int gid = blockIdx.x * 128 + threadIdx.x;
  const int b = gid >> 5;          // sample
  const int l32 = gid & 31;
  const int i = l32 & 15;          // row
  const int h = l32 >> 4;          // column half
  float hre[8], him[8];
#pragma unroll
  for (int jj = 0; jj < 8; jj++) {
    hre[jj] = Hre[i * 16 + h * 8 + jj];
    him[jj] = Him[i * 16 + h * 8 + jj];
  }
  const float mfi = mf[(long)b * 512 + i];
  float are, aim;
  if (st0 == 0) {
    are = ampr_in[b * 16 + i]; aim = ampi_in[b * 16 + i];
    float ss = are * are + aim * aim;
#pragma unroll
    for (int m = 1; m < 32; m <<= 1) ss += __shfl_xor(ss, m, 32);
    ss *= 0.5f;
    const float inv = 1.f / sqrtf(ss);
    are *= inv; aim *= inv;
  } else {
    are = ampS_r[b * 16 + i]; aim = ampS_i[b * 16 + i];
  }
#pragma unroll 1
  for (int st = st0; st < st0 + 25; ++st) {
    const float t = (float)st * 0.01f;
    const float fac = 1.f + t * mfi;
    const float dec = __expf(-t * 0.02f);   // exp(-t/50)
    float tre = are, tim = aim, rre = are, rim = aim;
#pragma unroll 1
    for (int k = 1; k <= 6; k++) {
      float w1r = 0.f, w1i = 0.f, w2r = 0.f, w2i = 0.f;
#pragma unroll
      for (int jj = 0; jj < 8; jj++) {
        const float vr = __shfl(tre, h * 8 + jj, 32);
        const float vi = __shfl(tim, h * 8 + jj, 32);
        w1r += hre[jj] * vr; w1i += hre[jj] * vi;
        w2r += him[jj] * vr; w2i += him[jj] * vi;
      }
      w1r += __shfl_xor(w1r, 16, 32);
      w1i += __shfl_xor(w1i, 16, 32);
      w2r += __shfl_xor(w2r, 16, 32);
      w2i += __shfl_xor(w2i, 16, 32);
      const float hr = w1r * fac - w2i;      // (Ht v)_re
      const float hi = w1i * fac + w2r;      // (Ht v)_im
      const float sk = 0.01f / (float)k;     // DT/k ; term *= -i*sk
      tre = sk * hi; tim = -sk * hr;
      rre += tre; rim += tim;
    }
    are = rre * dec; aim = rim * dec;
  }
  if (h == 0) {
    ampS_r[b * 16 + i] = are;
    ampS_i[b * 16 + i] = aim;
    if (bio) bio[(long)b * 576 + i] = f2b(are * are + aim * aim);   // obs
  }
}

__global__ void k_biofill(const float* __restrict__ mf, ushort* __restrict__ bio) {
  long i = (long)blockIdx.x * blockDim.x + threadIdx.x;
  if (i < (long)2048 * 512) {
    long b = i >> 9, k = i & 511;
    bio[b * 576 + 16 + k] = f2b(mf[i]);
  }
}

// ---------------------------------------------------------------------------
// m97-structure bf16 MFMA GEMM with (a) optional XCD-aware grid remap and
// (b) XOR-swizzled LDS fragments (pre-swizzled global src, linear gload_lds
// dest, swizzled ds_read). Involution: element (row,col8) lives at LDS elem
// (row>>3)*512 + (row&7)*64 + (col8 ^ (row&7))*8 within each operand tile.
// ---------------------------------------------------------------------------
template<int BT>
__global__ __launch_bounds__(256)
void k_gemm(const ushort* __restrict__ A, int lda,
            const ushort* __restrict__ W, int ldw,
            const float* __restrict__ bias,
            const float* __restrict__ Gg, int t0,
            float* __restrict__ Cf, int ldcf,
            ushort* __restrict__ Cb, int ldcb,
            int N, int K, int act, int swz) {
  constexpr int FR = BT / 32;
  constexpr int CH = BT / 32;
  __shared__ __align__(16) ushort lsA[BT * 64];
  __shared__ __align__(16) ushort lsB[BT * 64];
  const int tid = threadIdx.x;
  const int lane = tid & 63, w = tid >> 6;
  const int lr = lane & 15, lq = lane >> 4;
  const int wm = (w >> 1) * (BT / 2), wn = (w & 1) * (BT / 2);
  int bxb = blockIdx.x, byb = blockIdx.y;
  if (swz) {                                 // XCD-aware remap (grid 8 x 8k)
    const int id = byb * gridDim.x + bxb;
    const int xcd = id & 7, q = id >> 3;
    const int rows_per_xcd = gridDim.y >> 3;
    byb = xcd * rows_per_xcd + (q >> 3);     // gridDim.x == 8
    bxb = q & 7;
  }
  const int bm = byb * BT, bn = bxb * BT;
  const int srow = lane >> 3;                          // row within 8-row chunk
  const int scol = (((lane & 7) ^ srow)) * 8;          // PRE-SWIZZLED source col

  f32x4 acc[FR][FR];
#pragma unroll
  for (int i = 0; i < FR; i++)
#pragma unroll
    for (int j = 0; j < FR; j++) acc[i][j] = (f32x4){0.f, 0.f, 0.f, 0.f};

  for (int kk = 0; kk < K; kk += 64) {
#pragma unroll
    for (int c = 0; c < CH; c++) {
      const int ch = w * CH + c;
      const int r = ch * 8 + srow;
      gload16(A + (size_t)(bm + r) * lda + kk + scol, lsA + ch * 512);
      gload16(W + (size_t)(bn + r) * ldw + kk + scol, lsB + ch * 512);
    }
    __syncthreads();
    short8 af[FR][2], bf[FR][2];
#pragma unroll
    for (int mi = 0; mi < FR; mi++)
#pragma unroll
      for (int k2 = 0; k2 < 2; k2++) {
        const int row = wm + mi * 16 + lr;
        af[mi][k2] = *(const short8*)(lsA + (row >> 3) * 512 + (row & 7) * 64 +
                                      (((k2 * 4 + lq) ^ (row & 7)) * 8));
      }
#pragma unroll
    for (int ni = 0; ni < FR; ni++)
#pragma unroll
      for (int k2 = 0; k2 < 2; k2++) {
        const int row = wn + ni * 16 + lr;
        bf[ni][k2] = *(const short8*)(lsB + (row >> 3) * 512 + (row & 7) * 64 +
                                      (((k2 * 4 + lq) ^ (row & 7)) * 8));
      }
#pragma unroll
    for (int k2 = 0; k2 < 2; k2++)
#pragma unroll
      for (int mi = 0; mi < FR; mi++)
#pragma unroll
        for (int ni = 0; ni < FR; ni++)
          acc[mi][ni] = __builtin_amdgcn_mfma_f32_16x16x32_bf16(
              af[mi][k2], bf[ni][k2], acc[mi][ni], 0, 0, 0);
    __syncthreads();
  }

#pragma unroll
  for (int mi = 0; mi < FR; mi++) {
#pragma unroll
    for (int r = 0; r < 4; r++) {
      const int row = bm + wm + mi * 16 + lq * 4 + r;
      float gfac = 0.f; const float* ggrow = nullptr;
      if (Gg) {
        gfac = __expf(-(float)(t0 + (row >> 11)) * 0.1f);   // adapt(t)
        ggrow = Gg + (size_t)(row & 2047) * 1024;
      }
#pragma unroll
      for (int ni = 0; ni < FR; ni++) {
        const int col = bn + wn + ni * 16 + lr;
        if (col < N) {
          float v = acc[mi][ni][r];
          if (bias) v += bias[col];
          if (Gg)  v += gfac * ggrow[col];
          if (act == 1) v = fmaxf(v, 0.f);
          else if (act == 2) v = tanh_fast(v);
          else if (act == 3) v = sigf(v);
          if (Cf) Cf[(size_t)row * ldcf + col] = v;
          if (Cb) Cb[(size_t)row * ldcb + col] = f2b(v);
        }
      }
    }
  }
}

// ---------------------------------------------------------------------------
__global__ void k_noiseconv(const float* __restrict__ noise, ushort* __restrict__ dst, int t0) {
  long n = 10L * 2048 * 448;
  for (long idx = (long)blockIdx.x * blockDim.x + threadIdx.x; idx < n;
       idx += (long)gridDim.x * blockDim.x) {
    int r = (int)(idx % 448);
    long row = idx / 448;
    int b = (int)(row & 2047);
    int tl = (int)(row >> 11);
    ushort v = 0;
    if (r < 400)
      v = f2b(__builtin_nontemporal_load(&noise[((long)b * 50 + t0 + tl) * 400 + r]));
    dst[idx] = v;
  }
}

// ---------------------------------------------------------------------------
// LSTM recurrence (R13): block-staged IH + pipelined weight stream.
// ---------------------------------------------------------------------------
__global__ __launch_bounds__(512, 2)
void k_rec(const ushort* __restrict__ IH, const ushort* __restrict__ Whh,
           float* __restrict__ hstate, float* __restrict__ cstate,
           ushort* __restrict__ Hout, float* __restrict__ Xout, int t0) {
  __shared__ ushort h_lds[16][266];                      // odd dword stride
  __shared__ __align__(16) ushort ih_lds[4][16 * 1024];  // 4-step block, 128 KB
  const int tid = threadIdx.x;
  const int lane = tid & 63, w = tid >> 6;               // w in [0,8)
  const int lr = lane & 15, lq = lane >> 4;
  const int b0 = blockIdx.x * 16;
  const int wcols = w * 32;

  // resident gate-i weights: 2 col-groups x 8 k-chunks = 64 VGPRs
  short8 wres[2][8];
#pragma unroll
  for (int cg = 0; cg < 2; cg++) {
    const ushort* wp = Whh + (size_t)(wcols + cg * 16 + lr) * 256 + lq * 8;
#pragma unroll
    for (int kk = 0; kk < 8; kk++) wres[cg][kk] = *(const short8*)(wp + kk * 32);
  }

  float c_reg[2][4], h_reg[2][4];
#pragma unroll
  for (int cg = 0; cg < 2; cg++) {
    const int j = wcols + cg * 16 + lr;
#pragma unroll
    for (int r = 0; r < 4; r++) {
      const int s = lq * 4 + r;
      float hv = hstate[(size_t)(b0 + s) * 256 + j];
      c_reg[cg][r] = cstate[(size_t)(b0 + s) * 256 + j];
      h_reg[cg][r] = hv;
      h_lds[s][j] = f2b(hv);
    }
  }
  __syncthreads();

#define LOADB(buf, g, cg) { \
  const ushort* wp_ = Whh + (size_t)((g) * 256 + wcols + (cg) * 16 + lr) * 256 + lq * 8; \
  _Pragma("unroll") for (int kk = 0; kk < 8; kk++) (buf)[kk] = *(const short8*)(wp_ + kk * 32); }
#define MFMAB(buf, g, cg) { \
  _Pragma("unroll") for (int kk = 0; kk < 8; kk++) \
    acc[cg][g] = __builtin_amdgcn_mfma_f32_16x16x32_bf16(af[kk], (buf)[kk], acc[cg][g], 0, 0, 0); }
#define MFMAR(cg) { \
  _Pragma("unroll") for (int kk = 0; kk < 8; kk++) \
    acc[cg][0] = __builtin_amdgcn_mfma_f32_16x16x32_bf16(af[kk], wres[cg][kk], acc[cg][0], 0, 0, 0); }

  for (int blk = 0; blk < 10; blk += 4) {
    const int nst = (10 - blk) < 4 ? (10 - blk) : 4;
    // burst-stage nst steps of IH (nst x 32 KB) via global_load_lds
    for (int si = 0; si < nst; si++) {
      const ushort* src = IH + ((size_t)(blk + si) * 2048 + b0) * 1024;
#pragma unroll
      for (int u = 0; u < 4; u++) {
        const int bi = u * 8 + w;
        gload16(src + (size_t)bi * 512 + lane * 8, &ih_lds[si][bi * 512]);
      }
    }
    __syncthreads();   // stage drained; h_lds from prev step visible

    for (int i2 = 0; i2 < nst; i2++) {
      const int tl = blk + i2;
      const ushort* ihc = ih_lds[i2];
      // A fragments of h
      short8 af[8];
#pragma unroll
      for (int kk = 0; kk < 8; kk++)
        af[kk] = *(const short8*)(&h_lds[lr][kk * 32 + lq * 8]);
      __syncthreads();   // barrier-A: af reads done -> h_lds may be overwritten

      f32x4 acc[2][4];
#pragma unroll
      for (int cg = 0; cg < 2; cg++)
#pragma unroll
        for (int g = 0; g < 4; g++) acc[cg][g] = (f32x4){0.f, 0.f, 0.f, 0.f};

      // pipelined weight stream: 2-deep register dbuf, gate-i as latency cover
      short8 wb0[8], wb1[8];
      LOADB(wb0, 1, 0);
      LOADB(wb1, 1, 1);
      MFMAR(0);            // resident gate-i col-group 0 (no loads)
      MFMAR(1);            // resident gate-i col-group 1
      MFMAB(wb0, 1, 0);
      LOADB(wb0, 2, 0);
      MFMAB(wb1, 1, 1);
      LOADB(wb1, 2, 1);
      MFMAB(wb0, 2, 0);
      LOADB(wb0, 3, 0);
      MFMAB(wb1, 2, 1);
      LOADB(wb1, 3, 1);
      MFMAB(wb0, 3, 0);
      MFMAB(wb1, 3, 1);

      const int t = t0 + tl;
#pragma unroll
      for (int cg = 0; cg < 2; cg++) {
        const int j = wcols + cg * 16 + lr;
#pragma unroll
        for (int r = 0; r < 4; r++) {
          const int s = lq * 4 + r;
          const float zi = acc[cg][0][r] + b2f(ihc[s * 1024 + j]);
          const float zf = acc[cg][1][r] + b2f(ihc[s * 1024 + 256 + j]);
          const float zg = acc[cg][2][r] + b2f(ihc[s * 1024 + 512 + j]);
          const float zo = acc[cg][3][r] + b2f(ihc[s * 1024 + 768 + j]);
          const float ig = sigf(zi), fg = sigf(zf), gg = tanh_fast(zg), og = sigf(zo);
          const float c = fg * c_reg[cg][r] + ig * gg;
          c_reg[cg][r] = c;
          const float h = og * tanh_fast(c);
          h_reg[cg][r] = h;
          h_lds[s][j] = f2b(h);
          if (Hout) Hout[((size_t)t * 2048 + b0 + s) * 256 + j] = f2b(h);
          if (Xout)
            __builtin_nontemporal_store(h, &Xout[((size_t)(b0 + s) * 50 + t) * 256 + j]);
        }
      }
      __syncthreads();   // barrier-B: h visible before next step's af reads
    }
  }
#undef LOADB
#undef MFMAB
#undef MFMAR
#pragma unroll
  for (int cg = 0; cg < 2; cg++) {
    const int j = wcols + cg * 16 + lr;
#pragma unroll
    for (int r = 0; r < 4; r++) {
      const int s = lq * 4 + r;
      hstate[(size_t)(b0 + s) * 256 + j] = h_reg[cg][r];
      cstate[(size_t)(b0 + s) * 256 + j] = c_reg[cg][r];
    }
  }
}

// ---------------------------------------------------------------------------
__global__ void k_cffill(const float* __restrict__ hT, const ushort* __restrict__ recb,
                         ushort* __restrict__ cf) {
  long i = (long)blockIdx.x * blockDim.x + threadIdx.x;
  if (i < (long)2048 * 656) {
    long b = i / 656; int c = (int)(i % 656);
    cf[b * 704 + c] = (c < 256) ? f2b(hT[b * 256 + c]) : recb[b * 448 + (c - 256)];
  }
}

__global__ __launch_bounds__(256)
void k_cons(const float* __restrict__ c3, const float* __restrict__ w4,
            const float* __restrict__ b4, float* __restrict__ out) {
  __shared__ float red[256];
  float accv = 0.f;
  for (int b = threadIdx.x; b < 2048; b += 256) {
    float d = b4[0];
#pragma unroll
    for (int k = 0; k < 64; k++) d += c3[(long)b * 64 + k] * w4[k];
    accv += sigf(d);
  }
  red[threadIdx.x] = accv; __syncthreads();
  for (int s = 128; s > 0; s >>= 1) {
    if (threadIdx.x < s) red[threadIdx.x] += red[threadIdx.x + s];
    __syncthreads();
  }
  if (threadIdx.x == 0) out[0] = red[0] * (1.f / 2048.f);
}

__global__ __launch_bounds__(256)
void k_val(const float* __restrict__ x, float* __restrict__ out) {
  __shared__ float red[256];
  const float* p = x + (size_t)blockIdx.x * 12800;
  float a = 0.f;
  for (int i = threadIdx.x; i < 12800; i += 256) a += tanh_fast(p[i]);
  red[threadIdx.x] = a; __syncthreads();
  for (int s = 128; s > 0; s >>= 1) {
    if (threadIdx.x < s) red[threadIdx.x] += red[threadIdx.x + s];
    __syncthreads();
  }
  if (threadIdx.x == 0) out[blockIdx.x] = red[0] * (1.f / 12800.f);
}

// ---------------------------------------------------------------------------
// entanglement entropy: in-register unrolled 8x8 Jacobi
// ---------------------------------------------------------------------------
__global__ __launch_bounds__(64)
void k_ent(const float* __restrict__ ar, const float* __restrict__ ai,
           float* __restrict__ partial) {
  __shared__ float red[64];
  const int tid = threadIdx.x;
  const int b = blockIdx.x * 64 + tid;
  float vr[16], vi[16];
#pragma unroll
  for (int i = 0; i < 16; i++) { vr[i] = ar[b * 16 + i]; vi[i] = ai[b * 16 + i]; }
  float m[64];   // 8x8, compile-time indexed only -> registers
#pragma unroll
  for (int j = 0; j < 4; j++)
#pragma unroll
    for (int k = 0; k < 4; k++) {
      float re = 0.f, im = 0.f;
#pragma unroll
      for (int i = 0; i < 4; i++) {
        float xr = vr[i * 4 + j], xi = vi[i * 4 + j];
        float yr = vr[i * 4 + k], yi = vi[i * 4 + k];
        re += xr * yr + xi * yi;
        im += xi * yr - xr * yi;
      }
      m[j * 8 + k] = re;
      m[j * 8 + (k + 4)] = -im;
      m[(j + 4) * 8 + k] = im;
      m[(j + 4) * 8 + (k + 4)] = re;
    }
#pragma unroll 1
  for (int sweep = 0; sweep < 6; ++sweep) {
#pragma unroll
    for (int p = 0; p < 7; p++) {
#pragma unroll
      for (int q = p + 1; q < 8; q++) {
        const float apq = m[p * 8 + q];
        if (fabsf(apq) > 1e-28f) {
          const float app = m[p * 8 + p], aqq = m[q * 8 + q];
          const float tau = (aqq - app) / (2.f * apq);
          const float tt = (tau >= 0.f ? 1.f : -1.f) /
                           (fabsf(tau) + sqrtf(1.f + tau * tau));
          const float cc = 1.f / sqrtf(1.f + tt * tt);
          const float ssn = tt * cc;
#pragma unroll
          for (int k2 = 0; k2 < 8; k2++) {
            const float mp = m[p * 8 + k2], mq = m[q * 8 + k2];
            m[p * 8 + k2] = cc * mp - ssn * mq;
            m[q * 8 + k2] = ssn * mp + cc * mq;
          }
#pragma unroll
          for (int k2 = 0; k2 < 8; k2++) {
            const float mp = m[k2 * 8 + p], mq = m[k2 * 8 + q];
            m[k2 * 8 + p] = cc * mp - ssn * mq;
            m[k2 * 8 + q] = ssn * mp + cc * mq;
          }
        }
      }
    }
  }
  float e = 0.f;
#pragma unroll
  for (int k2 = 0; k2 < 8; k2++) {
    const float lam = fmaxf(m[k2 * 8 + k2], 1e-12f);
    e -= lam * logf(lam);
  }
  red[tid] = e; __syncthreads();
  for (int s = 32; s > 0; s >>= 1) {
    if (tid < s) red[tid] += red[tid + s];
    __syncthreads();
  }
  if (tid == 0) partial[blockIdx.x] = red[0];
}

__global__ void k_entfin(const float* __restrict__ partial, float* __restrict__ out) {
  if (threadIdx.x == 0) {
    float s = 0.f;
    for (int i = 0; i < 32; i++) s += partial[i];
    out[0] = s * (0.5f / 2048.f);
  }
}

// ---------------------------------------------------------------------------
extern "C" void kernel_launch(void* const* d_in, const int* in_sizes, int n_in,
                              void* d_out, int out_size, void* d_ws, size_t ws_size,
                              hipStream_t stream) {
  (void)in_sizes; (void)n_in; (void)out_size; (void)ws_size;
  const float* mf    = (const float*)d_in[0];
  const float* noise = (const float*)d_in[1];
  const float* ampr  = (const float*)d_in[2];
  const float* ampi  = (const float*)d_in[3];
  const float* Hre   = (const float*)d_in[4];
  const float* Him   = (const float*)d_in[5];
  const float* gpc   = (const float*)d_in[6];
  const float* bw1 = (const float*)d_in[7];  const float* bb1 = (const float*)d_in[8];
  const float* bw2 = (const float*)d_in[9];  const float* bb2 = (const float*)d_in[10];
  const float* bw3 = (const float*)d_in[11]; const float* bb3 = (const float*)d_in[12];
  const float* Wih[3] = {(const float*)d_in[13], (const float*)d_in[17], (const float*)d_in[21]};
  const float* Whh[3] = {(const float*)d_in[14], (const float*)d_in[18], (const float*)d_in[22]};
  const float* bih[3] = {(const float*)d_in[15], (const float*)d_in[19], (const float*)d_in[23]};
  const float* bhh[3] = {(const float*)d_in[16], (const float*)d_in[20], (const float*)d_in[24]};
  const float* cw1 = (const float*)d_in[25]; const float* cb1 = (const float*)d_in[26];
  const float* cw2 = (const float*)d_in[27]; const float* cb2 = (const float*)d_in[28];
  const float* cw3 = (const float*)d_in[29]; const float* cb3 = (const float*)d_in[30];
  const float* cw4 = (const float*)d_in[31]; const float* cb4 = (const float*)d_in[32];

  float* out = (float*)d_out;
  float* out_rec  = out;                    // [2048][400]
  float* out_seq  = out + 819200;           // [2048][50][256]
  float* out_val  = out + 27033600;         // [2048]
  float* out_cons = out + 27035648;
  float* out_ent  = out + 27035649;

  char* ws = (char*)d_ws;
  size_t off = 0;
  auto alloc = [&](size_t bytes) -> char* {
    char* p = ws + off; off += (bytes + 255) & ~(size_t)255; return p;
  };
  ushort* WB1   = (ushort*)alloc((size_t)256 * 576 * 2);
  ushort* WB2   = (ushort*)alloc((size_t)128 * 256 * 2);
  ushort* WB3   = (ushort*)alloc((size_t)512 * 128 * 2);
  ushort* WIH0  = (ushort*)alloc((size_t)1024 * 448 * 2);
  ushort* WIH0S = (ushort*)alloc((size_t)1024 * 448 * 2);
  ushort* WIH1  = (ushort*)alloc((size_t)1024 * 256 * 2);
  ushort* WIH2  = (ushort*)alloc((size_t)1024 * 256 * 2);
  ushort* WHH0  = (ushort*)alloc((size_t)1024 * 256 * 2);
  ushort* WHH1  = (ushort*)alloc((size_t)1024 * 256 * 2);
  ushort* WHH2  = (ushort*)alloc((size_t)1024 * 256 * 2);
  ushort* WC1   = (ushort*)alloc((size_t)512 * 704 * 2);
  ushort* WC2   = (ushort*)alloc((size_t)256 * 512 * 2);
  ushort* WC3   = (ushort*)alloc((size_t)128 * 256 * 2);
  float*  BSUM  = (float*)alloc((size_t)3 * 1024 * 4);
  ushort* BIO   = (ushort*)alloc((size_t)2048 * 576 * 2);
  ushort* H1B   = (ushort*)alloc((size_t)2048 * 256 * 2);
  ushort* H2B   = (ushort*)alloc((size_t)2048 * 128 * 2);
  ushort* RECB  = (ushort*)alloc((size_t)2048 * 448 * 2);
  float*  GG    = (float*)alloc((size_t)2048 * 1024 * 4);
  float*  AMPR  = (float*)alloc((size_t)2048 * 16 * 4);
  float*  AMPI  = (float*)alloc((size_t)2048 * 16 * 4);
  ushort* NCH   = (ushort*)alloc((size_t)10 * 2048 * 448 * 2);
  ushort* IHC   = (ushort*)alloc((size_t)10 * 2048 * 1024 * 2);
  ushort* HBUF  = (ushort*)alloc((size_t)50 * 2048 * 256 * 2);
  float*  HST   = (float*)alloc((size_t)2048 * 256 * 4);
  float*  CST   = (float*)alloc((size_t)2048 * 256 * 4);   // adjacent to HST
  ushort* CFB   = (ushort*)alloc((size_t)2048 * 704 * 2);
  ushort* C1B   = (ushort*)alloc((size_t)2048 * 512 * 2);
  ushort* C2B   = (ushort*)alloc((size_t)2048 * 256 * 2);
  float*  C3F   = (float*)alloc((size_t)2048 * 64 * 4);
  float*  ENTP  = (float*)alloc((size_t)32 * 4);

  hipMemsetAsync(BIO,  0, (size_t)2048 * 576 * 2, stream);
  hipMemsetAsync(RECB, 0, (size_t)2048 * 448 * 2, stream);
  hipMemsetAsync(CFB,  0, (size_t)2048 * 704 * 2, stream);

  auto convw = [&](const float* src, ushort* dst, int sr, int dr, int sc, int dc,
                   const float* scale, int mode) {
    long n = (long)dr * dc;
    int blocks = (int)((n + 255) / 256); if (blocks > 2048) blocks = 2048;
    hipLaunchKernelGGL(k_convw, dim3(blocks), dim3(256), 0, stream,
                       src, dst, sr, dr, sc, dc, scale, mode);
  };
  convw(bw1, WB1, 256, 256, 528, 576, nullptr, 0);
  convw(bw2, WB2, 128, 128, 256, 256, nullptr, 0);
  convw(bw3, WB3, 400, 512, 128, 128, nullptr, 0);
  convw(Wih[0], WIH0,  1024, 1024, 400, 448, nullptr, 0);
  convw(Wih[0], WIH0S, 1024, 1024, 400, 448, gpc, 1);   // fold sigmoid(gpc)
  convw(Wih[1], WIH1, 1024, 1024, 256, 256, nullptr, 0);
  convw(Wih[2], WIH2, 1024, 1024, 256, 256, nullptr, 0);
  convw(Whh[0], WHH0, 1024, 1024, 256, 256, nullptr, 0);
  convw(Whh[1], WHH1, 1024, 1024, 256, 256, nullptr, 0);
  convw(Whh[2], WHH2, 1024, 1024, 256, 256, nullptr, 0);
  convw(cw1, WC1, 512, 512, 656, 704, nullptr, 0);
  convw(cw2, WC2, 256, 256, 512, 512, nullptr, 0);
  convw(cw3, WC3,  64, 128, 256, 256, nullptr, 0);
  for (int l = 0; l < 3; l++)
    hipLaunchKernelGGL(k_vadd, dim3(4), dim3(256), 0, stream, bih[l], bhh[l], BSUM + l * 1024, 1024);

  // quantum: four 25-step chunks (state via AMPR/AMPI)
  for (int qc = 0; qc < 4; qc++)
    hipLaunchKernelGGL(k_quantum, dim3(512), dim3(128), 0, stream,
                       ampr, ampi, Hre, Him, mf,
                       (qc == 3 ? BIO : (ushort*)nullptr), AMPR, AMPI, qc * 25);
  hipLaunchKernelGGL(k_biofill, dim3(4096), dim3(256), 0, stream, mf, BIO);

  auto gemm = [&](bool big, const ushort* A, int lda, const ushort* W, int ldw,
                  const float* bias, const float* Gg, int t0, float* Cf, int ldcf,
                  ushort* Cb, int ldcb, int M, int N, int K, int act) {
    if (big) {
      dim3 grid((N + 127) / 128, M / 128);
      const int swz = (grid.x == 8 && (grid.y & 7) == 0) ? 1 : 0;
      hipLaunchKernelGGL(k_gemm<128>, grid, dim3(256), 0, stream,
                         A, lda, W, ldw, bias, Gg, t0, Cf, ldcf, Cb, ldcb, N, K, act, swz);
    } else {
      dim3 grid((N + 63) / 64, M / 64);
      hipLaunchKernelGGL(k_gemm<64>, grid, dim3(256), 0, stream,
                         A, lda, W, ldw, bias, Gg, t0, Cf, ldcf, Cb, ldcb, N, K, act, 0);
    }
  };

  // receptor MLP
  gemm(false, BIO, 576, WB1, 576, bb1, nullptr, 0, nullptr, 0, H1B, 256, 2048, 256, 576, 1);
  gemm(false, H1B, 256, WB2, 256, bb2, nullptr, 0, nullptr, 0, H2B, 128, 2048, 128, 256, 2);
  gemm(false, H2B, 128, WB3, 128, bb3, nullptr, 0, out_rec, 400, RECB, 448, 2048, 400, 128, 3);
  // Gg = (receptor * sigmoid(gpc)) @ Wih0^T
  gemm(false, RECB, 448, WIH0S, 448, nullptr, nullptr, 0, GG, 1024, nullptr, 0, 2048, 1024, 448, 0);

  // 3-layer LSTM, chunked 10 timesteps
  for (int l = 0; l < 3; l++) {
    hipMemsetAsync(HST, 0, (size_t)2048 * 256 * 4 * 2, stream);   // HST + CST
    for (int c = 0; c < 5; c++) {
      int t0 = c * 10;
      if (l == 0) {
        hipLaunchKernelGGL(k_noiseconv, dim3(8192), dim3(256), 0, stream, noise, NCH, t0);
        gemm(true, NCH, 448, WIH0, 448, BSUM, GG, t0, nullptr, 0, IHC, 1024, 20480, 1024, 448, 0);
      } else {
        const ushort* Aip = HBUF + (size_t)t0 * 2048 * 256;
        gemm(true, Aip, 256, (l == 1 ? WIH1 : WIH2), 256, BSUM + l * 1024, nullptr, 0,
             nullptr, 0, IHC, 1024, 20480, 1024, 256, 0);
      }
      hipLaunchKernelGGL(k_rec, dim3(128), dim3(512), 0, stream,
                         IHC, (l == 0 ? WHH0 : l == 1 ? WHH1 : WHH2), HST, CST,
                         (l < 2 ? HBUF : (ushort*)nullptr),
                         (l == 2 ? out_seq : (float*)nullptr), t0);
    }
  }

  // consumer MLP
  hipLaunchKernelGGL(k_cffill, dim3(5256), dim3(256), 0, stream, HST, RECB, CFB);
  gemm(false, CFB, 704, WC1, 704, cb1, nullptr, 0, nullptr, 0, C1B, 512, 2048, 512, 704, 1);
  gemm(false, C1B, 512, WC2, 512, cb2, nullptr, 0, nullptr, 0, C2B, 256, 2048, 256, 512, 1);
  gemm(false, C2B, 256, WC3, 256, cb3, nullptr, 0, C3F, 64, nullptr, 0, 2048, 64, 256, 2);
  hipLaunchKernelGGL(k_cons, dim3(1), dim3(256), 0, stream, C3F, cw4, cb4, out_cons);

  // valence + entropy
  hipLaunchKernelGGL(k_val, dim3(2048), dim3(256), 0, stream, out_seq, out_val);
  hipLaunchKernelGGL(k_ent, dim3(32), dim3(64), 0, stream, AMPR, AMPI, ENTP);
  hipLaunchKernelGGL(k_entfin, dim3(1), dim3(32), 0, stream, ENTP, out_ent);
}

// Round 15
// 3178.061 us; speedup vs baseline: 1.4486x; 1.0475x over previous
//
#include <hip/hip_runtime.h>
#include <stdint.h>

// ---------------------------------------------------------------------------
// QuantumOlfactoryReceptor: full pipeline
// Round 15: k_gemm triple fix (profile: latency-bound, GG-epilogue overfetch):
//  (1) 2-phase LDS double-buffer: stage(t+1) issued BEFORE compute(t), one
//      barrier per iter -> per-iter cost max(stage,compute) not sum.
//  (2) b-aligned XCD remap: XCD k owns b-blocks {2k,2k+1} across all t ->
//      GG footprint/XCD 8MB -> 1MB (A stays 2.3MB).
//  (3) GG stored bf16 (halves its traffic; negligible precision cost).
// ---------------------------------------------------------------------------

using short8 = __attribute__((ext_vector_type(8))) short;
using f32x4  = __attribute__((ext_vector_type(4))) float;

#define DEV static __device__ __forceinline__

typedef const __attribute__((address_space(1))) void GV;
typedef __attribute__((address_space(3))) void LV;
DEV void gload16(const void* g, void* l) {
  __builtin_amdgcn_global_load_lds((GV*)g, (LV*)l, 16, 0, 0);
}

DEV ushort f2b(float x) {                       // f32 -> bf16 RNE
  union { float f; uint32_t u; } v; v.f = x;
  uint32_t r = v.u + 0x7FFFu + ((v.u >> 16) & 1u);
  return (ushort)(r >> 16);
}
DEV float b2f(ushort x) {
  union { uint32_t u; float f; } v; v.u = ((uint32_t)x) << 16; return v.f;
}
DEV float sigf(float x) { return 1.f / (1.f + __expf(-x)); }
DEV float tanh_fast(float x) {
  float xc = fminf(9.f, fmaxf(-9.f, x));
  float e = __expf(2.f * xc);
  return (e - 1.f) / (e + 1.f);
}

// ---------------------------------------------------------------------------
__global__ void k_convw(const float* __restrict__ src, ushort* __restrict__ dst,
                        int sr, int dr, int sc, int dc,
                        const float* __restrict__ scale, int mode) {
  long n = (long)dr * dc;
  for (long idx = (long)blockIdx.x * blockDim.x + threadIdx.x; idx < n;
       idx += (long)gridDim.x * blockDim.x) {
    int r = (int)(idx / dc), c = (int)(idx % dc);
    float v = 0.f;
    if (r < sr && c < sc) {
      v = src[(long)r * sc + c];
      if (mode == 1) v *= sigf(scale[c]);
    }
    dst[idx] = f2b(v);
  }
}

__global__ void k_vadd(const float* __restrict__ a, const float* __restrict__ b,
                       float* __restrict__ o, int n) {
  int i = blockIdx.x * blockDim.x + threadIdx.x;
  if (i < n) o[i] = a[i] + b[i];
}

// ---------------------------------------------------------------------------
// quantum evolution: 32 lanes per sample, Taylor action of expm, 6 terms.
// Runs steps [st0, st0+25); state in ampS_r/ampS_i.
// ---------------------------------------------------------------------------
__global__ __launch_bounds__(128)
void k_quantum(const float* __restrict__ ampr_in, const float* __restrict__ ampi_in,
               const float* __restrict__ Hre, const float* __restrict__ Him,
               const float* __restrict__ mf,
               ushort* __restrict__ bio, float* __restrict__ ampS_r,
               float* __restrict__ ampS_i, int st0) {
  const int gid = blockIdx.x * 128 + threadIdx.x;
  const int b = gid >> 5;          // sample
  const int l32 = gid & 31;
  const int i = l32 & 15;          // row
  const int h = l32 >> 4;          // column half
  float hre[8], him[8];
#pragma unroll
  for (int jj = 0; jj < 8; jj++) {
    hre[jj] = Hre[i * 16 + h * 8 + jj];
    him[jj] = Him[i * 16 + h * 8 + jj];
  }
  const float mfi = mf[(long)b * 512 + i];
  float are, aim;
  if (st0 == 0) {
    are = ampr_in[b * 16 + i]; aim = ampi_in[b * 16 + i];
    float ss = are * are + aim * aim;
#pragma unroll
    for (int m = 1; m < 32; m <<= 1) ss += __shfl_xor(ss, m, 32);
    ss *= 0.5f;
    const float inv = 1.f / sqrtf(ss);
    are *= inv; aim *= inv;
  } else {
    are = ampS_r[b * 16 + i]; aim = ampS_i[b * 16 + i];
  }
#pragma unroll 1
  for (int st = st0; st < st0 + 25; ++st) {
    const float t = (float)st * 0.01f;
    const float fac = 1.f + t * mfi;
    const float dec = __expf(-t * 0.02f);   // exp(-t/50)
    float tre = are, tim = aim, rre = are, rim = aim;
#pragma unroll 1
    for (int k = 1; k <= 6; k++) {
      float w1r = 0.f, w1i = 0.f, w2r = 0.f, w2i = 0.f;
#pragma unroll
      for (int jj = 0; jj < 8; jj++) {
        const float vr = __shfl(tre, h * 8 + jj, 32);
        const float vi = __shfl(tim, h * 8 + jj, 32);
        w1r += hre[jj] * vr; w1i += hre[jj] * vi;
        w2r += him[jj] * vr; w2i += him[jj] * vi;
      }
      w1r += __shfl_xor(w1r, 16, 32);
      w1i += __shfl_xor(w1i, 16, 32);
      w2r += __shfl_xor(w2r, 16, 32);
      w2i += __shfl_xor(w2i, 16, 32);
      const float hr = w1r * fac - w2i;      // (Ht v)_re
      const float hi = w1i * fac + w2r;      // (Ht v)_im
      const float sk = 0.01f / (float)k;     // DT/k ; term *= -i*sk
      tre = sk * hi; tim = -sk * hr;
      rre += tre; rim += tim;
    }
    are = rre * dec; aim = rim * dec;
  }
  if (h == 0) {
    ampS_r[b * 16 + i] = are;
    ampS_i[b * 16 + i] = aim;
    if (bio) bio[(long)b * 576 + i] = f2b(are * are + aim * aim);   // obs
  }
}

__global__ void k_biofill(const float* __restrict__ mf, ushort* __restrict__ bio) {
  long i = (long)blockIdx.x * blockDim.x + threadIdx.x;
  if (i < (long)2048 * 512) {
    long b = i >> 9, k = i & 511;
    bio[b * 576 + 16 + k] = f2b(mf[i]);
  }
}

// ---------------------------------------------------------------------------
// bf16 MFMA GEMM: 2-phase LDS dbuf prefetch + XOR-swizzled fragments +
// optional b-aligned XCD remap. Gg (adapt term) is bf16.
// ---------------------------------------------------------------------------
template<int BT>
__global__ __launch_bounds__(256)
void k_gemm(const ushort* __restrict__ A, int lda,
            const ushort* __restrict__ W, int ldw,
            const float* __restrict__ bias,
            const ushort* __restrict__ Gg, int t0,
            float* __restrict__ Cf, int ldcf,
            ushort* __restrict__ Cb, int ldcb,
            int N, int K, int act, int swz) {
  constexpr int FR = BT / 32;
  constexpr int CH = BT / 32;
  __shared__ __align__(16) ushort lsA[2][BT * 64];
  __shared__ __align__(16) ushort lsB[2][BT * 64];
  const int tid = threadIdx.x;
  const int lane = tid & 63, w = tid >> 6;
  const int lr = lane & 15, lq = lane >> 4;
  const int wm = (w >> 1) * (BT / 2), wn = (w & 1) * (BT / 2);
  int bxb = blockIdx.x, byb = blockIdx.y;
  if (swz) {                      // b-aligned XCD remap (grid 8 x 16T)
    const int id = byb * gridDim.x + bxb;
    const int xcd = id & 7, q = id >> 3;
    byb = (q >> 4) * 16 + xcd * 2 + (q & 1);
    bxb = (q >> 1) & 7;
  }
  const int bm = byb * BT, bn = bxb * BT;
  const int srow = lane >> 3;                 // row within 8-row chunk
  const int scol = (((lane & 7) ^ srow)) * 8; // pre-swizzled source col

  auto stage = [&](int buf, int kk) {
#pragma unroll
    for (int c = 0; c < CH; c++) {
      const int ch = w * CH + c;
      const int r = ch * 8 + srow;
      gload16(A + (size_t)(bm + r) * lda + kk + scol, lsA[buf] + ch * 512);
      gload16(W + (size_t)(bn + r) * ldw + kk + scol, lsB[buf] + ch * 512);
    }
  };

  f32x4 acc[FR][FR];
#pragma unroll
  for (int i = 0; i < FR; i++)
#pragma unroll
    for (int j = 0; j < FR; j++) acc[i][j] = (f32x4){0.f, 0.f, 0.f, 0.f};

  stage(0, 0);
  __syncthreads();                            // tile 0 landed
  const int T = K >> 6;
  for (int t = 0; t < T; t++) {
    const int cur = t & 1;
    if (t + 1 < T) stage(cur ^ 1, (t + 1) * 64);   // prefetch next tile
    short8 af[FR][2], bf[FR][2];
#pragma unroll
    for (int mi = 0; mi < FR; mi++)
#pragma unroll
      for (int k2 = 0; k2 < 2; k2++) {
        const int row = wm + mi * 16 + lr;
        af[mi][k2] = *(const short8*)(lsA[cur] + (row >> 3) * 512 + (row & 7) * 64 +
                                      (((k2 * 4 + lq) ^ (row & 7)) * 8));
      }
#pragma unroll
    for (int ni = 0; ni < FR; ni++)
#pragma unroll
      for (int k2 = 0; k2 < 2; k2++) {
        const int row = wn + ni * 16 + lr;
        bf[ni][k2] = *(const short8*)(lsB[cur] + (row >> 3) * 512 + (row & 7) * 64 +
                                      (((k2 * 4 + lq) ^ (row & 7)) * 8));
      }
#pragma unroll
    for (int k2 = 0; k2 < 2; k2++)
#pragma unroll
      for (int mi = 0; mi < FR; mi++)
#pragma unroll
        for (int ni = 0; ni < FR; ni++)
          acc[mi][ni] = __builtin_amdgcn_mfma_f32_16x16x32_bf16(
              af[mi][k2], bf[ni][k2], acc[mi][ni], 0, 0, 0);
    __syncthreads();   // drains prefetch (vmcnt0) + guards lsX[cur] reuse
  }

#pragma unroll
  for (int mi = 0; mi < FR; mi++) {
#pragma unroll
    for (int r = 0; r < 4; r++) {
      const int row = bm + wm + mi * 16 + lq * 4 + r;
      float gfac = 0.f; const ushort* ggrow = nullptr;
      if (Gg) {
        gfac = __expf(-(float)(t0 + (row >> 11)) * 0.1f);   // adapt(t)
        ggrow = Gg + (size_t)(row & 2047) * 1024;
      }
#pragma unroll
      for (int ni = 0; ni < FR; ni++) {
        const int col = bn + wn + ni * 16 + lr;
        if (col < N) {
          float v = acc[mi][ni][r];
          if (bias) v += bias[col];
          if (Gg)  v += gfac * b2f(ggrow[col]);
          if (act == 1) v = fmaxf(v, 0.f);
          else if (act == 2) v = tanh_fast(v);
          else if (act == 3) v = sigf(v);
          if (Cf) Cf[(size_t)row * ldcf + col] = v;
          if (Cb) Cb[(size_t)row * ldcb + col] = f2b(v);
        }
      }
    }
  }
}

// ---------------------------------------------------------------------------
__global__ void k_noiseconv(const float* __restrict__ noise, ushort* __restrict__ dst, int t0) {
  long n = 10L * 2048 * 448;
  for (long idx = (long)blockIdx.x * blockDim.x + threadIdx.x; idx < n;
       idx += (long)gridDim.x * blockDim.x) {
    int r = (int)(idx % 448);
    long row = idx / 448;
    int b = (int)(row & 2047);
    int tl = (int)(row >> 11);
    ushort v = 0;
    if (r < 400)
      v = f2b(__builtin_nontemporal_load(&noise[((long)b * 50 + t0 + tl) * 400 + r]));
    dst[idx] = v;
  }
}

// ---------------------------------------------------------------------------
// LSTM recurrence (R13): block-staged IH + pipelined weight stream.
// ---------------------------------------------------------------------------
__global__ __launch_bounds__(512, 2)
void k_rec(const ushort* __restrict__ IH, const ushort* __restrict__ Whh,
           float* __restrict__ hstate, float* __restrict__ cstate,
           ushort* __restrict__ Hout, float* __restrict__ Xout, int t0) {
  __shared__ ushort h_lds[16][266];                      // odd dword stride
  __shared__ __align__(16) ushort ih_lds[4][16 * 1024];  // 4-step block, 128 KB
  const int tid = threadIdx.x;
  const int lane = tid & 63, w = tid >> 6;               // w in [0,8)
  const int lr = lane & 15, lq = lane >> 4;
  const int b0 = blockIdx.x * 16;
  const int wcols = w * 32;

  // resident gate-i weights: 2 col-groups x 8 k-chunks = 64 VGPRs
  short8 wres[2][8];
#pragma unroll
  for (int cg = 0; cg < 2; cg++) {
    const ushort* wp = Whh + (size_t)(wcols + cg * 16 + lr) * 256 + lq * 8;
#pragma unroll
    for (int kk = 0; kk < 8; kk++) wres[cg][kk] = *(const short8*)(wp + kk * 32);
  }

  float c_reg[2][4], h_reg[2][4];
#pragma unroll
  for (int cg = 0; cg < 2; cg++) {
    const int j = wcols + cg * 16 + lr;
#pragma unroll
    for (int r = 0; r < 4; r++) {
      const int s = lq * 4 + r;
      float hv = hstate[(size_t)(b0 + s) * 256 + j];
      c_reg[cg][r] = cstate[(size_t)(b0 + s) * 256 + j];
      h_reg[cg][r] = hv;
      h_lds[s][j] = f2b(hv);
    }
  }
  __syncthreads();

#define LOADB(buf, g, cg) { \
  const ushort* wp_ = Whh + (size_t)((g) * 256 + wcols + (cg) * 16 + lr) * 256 + lq * 8; \
  _Pragma("unroll") for (int kk = 0; kk < 8; kk++) (buf)[kk] = *(const short8*)(wp_ + kk * 32); }
#define MFMAB(buf, g, cg) { \
  _Pragma("unroll") for (int kk = 0; kk < 8; kk++) \
    acc[cg][g] = __builtin_amdgcn_mfma_f32_16x16x32_bf16(af[kk], (buf)[kk], acc[cg][g], 0, 0, 0); }
#define MFMAR(cg) { \
  _Pragma("unroll") for (int kk = 0; kk < 8; kk++) \
    acc[cg][0] = __builtin_amdgcn_mfma_f32_16x16x32_bf16(af[kk], wres[cg][kk], acc[cg][0], 0, 0, 0); }

  for (int blk = 0; blk < 10; blk += 4) {
    const int nst = (10 - blk) < 4 ? (10 - blk) : 4;
    // burst-stage nst steps of IH (nst x 32 KB) via global_load_lds
    for (int si = 0; si < nst; si++) {
      const ushort* src = IH + ((size_t)(blk + si) * 2048 + b0) * 1024;
#pragma unroll
      for (int u = 0; u < 4; u++) {
        const int bi = u * 8 + w;
        gload16(src + (size_t)bi * 512 + lane * 8, &ih_lds[si][bi * 512]);
      }
    }
    __syncthreads();   // stage drained; h_lds from prev step visible

    for (int i2 = 0; i2 < nst; i2++) {
      const int tl = blk + i2;
      const ushort* ihc = ih_lds[i2];
      // A fragments of h
      short8 af[8];
#pragma unroll
      for (int kk = 0; kk < 8; kk++)
        af[kk] = *(const short8*)(&h_lds[lr][kk * 32 + lq * 8]);
      __syncthreads();   // barrier-A: af reads done -> h_lds may be overwritten

      f32x4 acc[2][4];
#pragma unroll
      for (int cg = 0; cg < 2; cg++)
#pragma unroll
        for (int g = 0; g < 4; g++) acc[cg][g] = (f32x4){0.f, 0.f, 0.f, 0.f};

      // pipelined weight stream: 2-deep register dbuf, gate-i as latency cover
      short8 wb0[8], wb1[8];
      LOADB(wb0, 1, 0);
      LOADB(wb1, 1, 1);
      MFMAR(0);            // resident gate-i col-group 0 (no loads)
      MFMAR(1);            // resident gate-i col-group 1
      MFMAB(wb0, 1, 0);
      LOADB(wb0, 2, 0);
      MFMAB(wb1, 1, 1);
      LOADB(wb1, 2, 1);
      MFMAB(wb0, 2, 0);
      LOADB(wb0, 3, 0);
      MFMAB(wb1, 2, 1);
      LOADB(wb1, 3, 1);
      MFMAB(wb0, 3, 0);
      MFMAB(wb1, 3, 1);

      const int t = t0 + tl;
#pragma unroll
      for (int cg = 0; cg < 2; cg++) {
        const int j = wcols + cg * 16 + lr;
#pragma unroll
        for (int r = 0; r < 4; r++) {
          const int s = lq * 4 + r;
          const float zi = acc[cg][0][r] + b2f(ihc[s * 1024 + j]);
          const float zf = acc[cg][1][r] + b2f(ihc[s * 1024 + 256 + j]);
          const float zg = acc[cg][2][r] + b2f(ihc[s * 1024 + 512 + j]);
          const float zo = acc[cg][3][r] + b2f(ihc[s * 1024 + 768 + j]);
          const float ig = sigf(zi), fg = sigf(zf), gg = tanh_fast(zg), og = sigf(zo);
          const float c = fg * c_reg[cg][r] + ig * gg;
          c_reg[cg][r] = c;
          const float h = og * tanh_fast(c);
          h_reg[cg][r] = h;
          h_lds[s][j] = f2b(h);
          if (Hout) Hout[((size_t)t * 2048 + b0 + s) * 256 + j] = f2b(h);
          if (Xout)
            __builtin_nontemporal_store(h, &Xout[((size_t)(b0 + s) * 50 + t) * 256 + j]);
        }
      }
      __syncthreads();   // barrier-B: h visible before next step's af reads
    }
  }
#undef LOADB
#undef MFMAB
#undef MFMAR
#pragma unroll
  for (int cg = 0; cg < 2; cg++) {
    const int j = wcols + cg * 16 + lr;
#pragma unroll
    for (int r = 0; r < 4; r++) {
      const int s = lq * 4 + r;
      hstate[(size_t)(b0 + s) * 256 + j] = h_reg[cg][r];
      cstate[(size_t)(b0 + s) * 256 + j] = c_reg[cg][r];
    }
  }
}

// ---------------------------------------------------------------------------
__global__ void k_cffill(const float* __restrict__ hT, const ushort* __restrict__ recb,
                         ushort* __restrict__ cf) {
  long i = (long)blockIdx.x * blockDim.x + threadIdx.x;
  if (i < (long)2048 * 656) {
    long b = i / 656; int c = (int)(i % 656);
    cf[b * 704 + c] = (c < 256) ? f2b(hT[b * 256 + c]) : recb[b * 448 + (c - 256)];
  }
}

__global__ __launch_bounds__(256)
void k_cons(const float* __restrict__ c3, const float* __restrict__ w4,
            const float* __restrict__ b4, float* __restrict__ out) {
  __shared__ float red[256];
  float accv = 0.f;
  for (int b = threadIdx.x; b < 2048; b += 256) {
    float d = b4[0];
#pragma unroll
    for (int k = 0; k < 64; k++) d += c3[(long)b * 64 + k] * w4[k];
    accv += sigf(d);
  }
  red[threadIdx.x] = accv; __syncthreads();
  for (int s = 128; s > 0; s >>= 1) {
    if (threadIdx.x < s) red[threadIdx.x] += red[threadIdx.x + s];
    __syncthreads();
  }
  if (threadIdx.x == 0) out[0] = red[0] * (1.f / 2048.f);
}

__global__ __launch_bounds__(256)
void k_val(const float* __restrict__ x, float* __restrict__ out) {
  __shared__ float red[256];
  const float* p = x + (size_t)blockIdx.x * 12800;
  float a = 0.f;
  for (int i = threadIdx.x; i < 12800; i += 256) a += tanh_fast(p[i]);
  red[threadIdx.x] = a; __syncthreads();
  for (int s = 128; s > 0; s >>= 1) {
    if (threadIdx.x < s) red[threadIdx.x] += red[threadIdx.x + s];
    __syncthreads();
  }
  if (threadIdx.x == 0) out[blockIdx.x] = red[0] * (1.f / 12800.f);
}

// ---------------------------------------------------------------------------
// entanglement entropy: in-register unrolled 8x8 Jacobi
// ---------------------------------------------------------------------------
__global__ __launch_bounds__(64)
void k_ent(const float* __restrict__ ar, const float* __restrict__ ai,
           float* __restrict__ partial) {
  __shared__ float red[64];
  const int tid = threadIdx.x;
  const int b = blockIdx.x * 64 + tid;
  float vr[16], vi[16];
#pragma unroll
  for (int i = 0; i < 16; i++) { vr[i] = ar[b * 16 + i]; vi[i] = ai[b * 16 + i]; }
  float m[64];   // 8x8, compile-time indexed only -> registers
#pragma unroll
  for (int j = 0; j < 4; j++)
#pragma unroll
    for (int k = 0; k < 4; k++) {
      float re = 0.f, im = 0.f;
#pragma unroll
      for (int i = 0; i < 4; i++) {
        float xr = vr[i * 4 + j], xi = vi[i * 4 + j];
        float yr = vr[i * 4 + k], yi = vi[i * 4 + k];
        re += xr * yr + xi * yi;
        im += xi * yr - xr * yi;
      }
      m[j * 8 + k] = re;
      m[j * 8 + (k + 4)] = -im;
      m[(j + 4) * 8 + k] = im;
      m[(j + 4) * 8 + (k + 4)] = re;
    }
#pragma unroll 1
  for (int sweep = 0; sweep < 6; ++sweep) {
#pragma unroll
    for (int p = 0; p < 7; p++) {
#pragma unroll
      for (int q = p + 1; q < 8; q++) {
        const float apq = m[p * 8 + q];
        if (fabsf(apq) > 1e-28f) {
          const float app = m[p * 8 + p], aqq = m[q * 8 + q];
          const float tau = (aqq - app) / (2.f * apq);
          const float tt = (tau >= 0.f ? 1.f : -1.f) /
                           (fabsf(tau) + sqrtf(1.f + tau * tau));
          const float cc = 1.f / sqrtf(1.f + tt * tt);
          const float ssn = tt * cc;
#pragma unroll
          for (int k2 = 0; k2 < 8; k2++) {
            const float mp = m[p * 8 + k2], mq = m[q * 8 + k2];
            m[p * 8 + k2] = cc * mp - ssn * mq;
            m[q * 8 + k2] = ssn * mp + cc * mq;
          }
#pragma unroll
          for (int k2 = 0; k2 < 8; k2++) {
            const float mp = m[k2 * 8 + p], mq = m[k2 * 8 + q];
            m[k2 * 8 + p] = cc * mp - ssn * mq;
            m[k2 * 8 + q] = ssn * mp + cc * mq;
          }
        }
      }
    }
  }
  float e = 0.f;
#pragma unroll
  for (int k2 = 0; k2 < 8; k2++) {
    const float lam = fmaxf(m[k2 * 8 + k2], 1e-12f);
    e -= lam * logf(lam);
  }
  red[tid] = e; __syncthreads();
  for (int s = 32; s > 0; s >>= 1) {
    if (tid < s) red[tid] += red[tid + s];
    __syncthreads();
  }
  if (tid == 0) partial[blockIdx.x] = red[0];
}

__global__ void k_entfin(const float* __restrict__ partial, float* __restrict__ out) {
  if (threadIdx.x == 0) {
    float s = 0.f;
    for (int i = 0; i < 32; i++) s += partial[i];
    out[0] = s * (0.5f / 2048.f);
  }
}

// ---------------------------------------------------------------------------
extern "C" void kernel_launch(void* const* d_in, const int* in_sizes, int n_in,
                              void* d_out, int out_size, void* d_ws, size_t ws_size,
                              hipStream_t stream) {
  (void)in_sizes; (void)n_in; (void)out_size; (void)ws_size;
  const float* mf    = (const float*)d_in[0];
  const float* noise = (const float*)d_in[1];
  const float* ampr  = (const float*)d_in[2];
  const float* ampi  = (const float*)d_in[3];
  const float* Hre   = (const float*)d_in[4];
  const float* Him   = (const float*)d_in[5];
  const float* gpc   = (const float*)d_in[6];
  const float* bw1 = (const float*)d_in[7];  const float* bb1 = (const float*)d_in[8];
  const float* bw2 = (const float*)d_in[9];  const float* bb2 = (const float*)d_in[10];
  const float* bw3 = (const float*)d_in[11]; const float* bb3 = (const float*)d_in[12];
  const float* Wih[3] = {(const float*)d_in[13], (const float*)d_in[17], (const float*)d_in[21]};
  const float* Whh[3] = {(const float*)d_in[14], (const float*)d_in[18], (const float*)d_in[22]};
  const float* bih[3] = {(const float*)d_in[15], (const float*)d_in[19], (const float*)d_in[23]};
  const float* bhh[3] = {(const float*)d_in[16], (const float*)d_in[20], (const float*)d_in[24]};
  const float* cw1 = (const float*)d_in[25]; const float* cb1 = (const float*)d_in[26];
  const float* cw2 = (const float*)d_in[27]; const float* cb2 = (const float*)d_in[28];
  const float* cw3 = (const float*)d_in[29]; const float* cb3 = (const float*)d_in[30];
  const float* cw4 = (const float*)d_in[31]; const float* cb4 = (const float*)d_in[32];

  float* out = (float*)d_out;
  float* out_rec  = out;                    // [2048][400]
  float* out_seq  = out + 819200;           // [2048][50][256]
  float* out_val  = out + 27033600;         // [2048]
  float* out_cons = out + 27035648;
  float* out_ent  = out + 27035649;

  char* ws = (char*)d_ws;
  size_t off = 0;
  auto alloc = [&](size_t bytes) -> char* {
    char* p = ws + off; off += (bytes + 255) & ~(size_t)255; return p;
  };
  ushort* WB1   = (ushort*)alloc((size_t)256 * 576 * 2);
  ushort* WB2   = (ushort*)alloc((size_t)128 * 256 * 2);
  ushort* WB3   = (ushort*)alloc((size_t)512 * 128 * 2);
  ushort* WIH0  = (ushort*)alloc((size_t)1024 * 448 * 2);
  ushort* WIH0S = (ushort*)alloc((size_t)1024 * 448 * 2);
  ushort* WIH1  = (ushort*)alloc((size_t)1024 * 256 * 2);
  ushort* WIH2  = (ushort*)alloc((size_t)1024 * 256 * 2);
  ushort* WHH0  = (ushort*)alloc((size_t)1024 * 256 * 2);
  ushort* WHH1  = (ushort*)alloc((size_t)1024 * 256 * 2);
  ushort* WHH2  = (ushort*)alloc((size_t)1024 * 256 * 2);
  ushort* WC1   = (ushort*)alloc((size_t)512 * 704 * 2);
  ushort* WC2   = (ushort*)alloc((size_t)256 * 512 * 2);
  ushort* WC3   = (ushort*)alloc((size_t)128 * 256 * 2);
  float*  BSUM  = (float*)alloc((size_t)3 * 1024 * 4);
  ushort* BIO   = (ushort*)alloc((size_t)2048 * 576 * 2);
  ushort* H1B   = (ushort*)alloc((size_t)2048 * 256 * 2);
  ushort* H2B   = (ushort*)alloc((size_t)2048 * 128 * 2);
  ushort* RECB  = (ushort*)alloc((size_t)2048 * 448 * 2);
  ushort* GGB   = (ushort*)alloc((size_t)2048 * 1024 * 2);
  float*  AMPR  = (float*)alloc((size_t)2048 * 16 * 4);
  float*  AMPI  = (float*)alloc((size_t)2048 * 16 * 4);
  ushort* NCH   = (ushort*)alloc((size_t)10 * 2048 * 448 * 2);
  ushort* IHC   = (ushort*)alloc((size_t)10 * 2048 * 1024 * 2);
  ushort* HBUF  = (ushort*)alloc((size_t)50 * 2048 * 256 * 2);
  float*  HST   = (float*)alloc((size_t)2048 * 256 * 4);
  float*  CST   = (float*)alloc((size_t)2048 * 256 * 4);   // adjacent to HST
  ushort* CFB   = (ushort*)alloc((size_t)2048 * 704 * 2);
  ushort* C1B   = (ushort*)alloc((size_t)2048 * 512 * 2);
  ushort* C2B   = (ushort*)alloc((size_t)2048 * 256 * 2);
  float*  C3F   = (float*)alloc((size_t)2048 * 64 * 4);
  float*  ENTP  = (float*)alloc((size_t)32 * 4);

  hipMemsetAsync(BIO,  0, (size_t)2048 * 576 * 2, stream);
  hipMemsetAsync(RECB, 0, (size_t)2048 * 448 * 2, stream);
  hipMemsetAsync(CFB,  0, (size_t)2048 * 704 * 2, stream);

  auto convw = [&](const float* src, ushort* dst, int sr, int dr, int sc, int dc,
                   const float* scale, int mode) {
    long n = (long)dr * dc;
    int blocks = (int)((n + 255) / 256); if (blocks > 2048) blocks = 2048;
    hipLaunchKernelGGL(k_convw, dim3(blocks), dim3(256), 0, stream,
                       src, dst, sr, dr, sc, dc, scale, mode);
  };
  convw(bw1, WB1, 256, 256, 528, 576, nullptr, 0);
  convw(bw2, WB2, 128, 128, 256, 256, nullptr, 0);
  convw(bw3, WB3, 400, 512, 128, 128, nullptr, 0);
  convw(Wih[0], WIH0,  1024, 1024, 400, 448, nullptr, 0);
  convw(Wih[0], WIH0S, 1024, 1024, 400, 448, gpc, 1);   // fold sigmoid(gpc)
  convw(Wih[1], WIH1, 1024, 1024, 256, 256, nullptr, 0);
  convw(Wih[2], WIH2, 1024, 1024, 256, 256, nullptr, 0);
  convw(Whh[0], WHH0, 1024, 1024, 256, 256, nullptr, 0);
  convw(Whh[1], WHH1, 1024, 1024, 256, 256, nullptr, 0);
  convw(Whh[2], WHH2, 1024, 1024, 256, 256, nullptr, 0);
  convw(cw1, WC1, 512, 512, 656, 704, nullptr, 0);
  convw(cw2, WC2, 256, 256, 512, 512, nullptr, 0);
  convw(cw3, WC3,  64, 128, 256, 256, nullptr, 0);
  for (int l = 0; l < 3; l++)
    hipLaunchKernelGGL(k_vadd, dim3(4), dim3(256), 0, stream, bih[l], bhh[l], BSUM + l * 1024, 1024);

  // quantum: four 25-step chunks (state via AMPR/AMPI)
  for (int qc = 0; qc < 4; qc++)
    hipLaunchKernelGGL(k_quantum, dim3(512), dim3(128), 0, stream,
                       ampr, ampi, Hre, Him, mf,
                       (qc == 3 ? BIO : (ushort*)nullptr), AMPR, AMPI, qc * 25);
  hipLaunchKernelGGL(k_biofill, dim3(4096), dim3(256), 0, stream, mf, BIO);

  auto gemm = [&](bool big, const ushort* A, int lda, const ushort* W, int ldw,
                  const float* bias, const ushort* Gg, int t0, float* Cf, int ldcf,
                  ushort* Cb, int ldcb, int M, int N, int K, int act) {
    if (big) {
      dim3 grid((N + 127) / 128, M / 128);
      const int swz = (grid.x == 8 && (grid.y & 15) == 0) ? 1 : 0;
      hipLaunchKernelGGL(k_gemm<128>, grid, dim3(256), 0, stream,
                         A, lda, W, ldw, bias, Gg, t0, Cf, ldcf, Cb, ldcb, N, K, act, swz);
    } else {
      dim3 grid((N + 63) / 64, M / 64);
      hipLaunchKernelGGL(k_gemm<64>, grid, dim3(256), 0, stream,
                         A, lda, W, ldw, bias, Gg, t0, Cf, ldcf, Cb, ldcb, N, K, act, 0);
    }
  };

  // receptor MLP
  gemm(false, BIO, 576, WB1, 576, bb1, nullptr, 0, nullptr, 0, H1B, 256, 2048, 256, 576, 1);
  gemm(false, H1B, 256, WB2, 256, bb2, nullptr, 0, nullptr, 0, H2B, 128, 2048, 128, 256, 2);
  gemm(false, H2B, 128, WB3, 128, bb3, nullptr, 0, out_rec, 400, RECB, 448, 2048, 400, 128, 3);
  // GGB = (receptor * sigmoid(gpc)) @ Wih0^T   (bf16)
  gemm(false, RECB, 448, WIH0S, 448, nullptr, nullptr, 0, nullptr, 0, GGB, 1024, 2048, 1024, 448, 0);

  // 3-layer LSTM, chunked 10 timesteps
  for (int l = 0; l < 3; l++) {
    hipMemsetAsync(HST, 0, (size_t)2048 * 256 * 4 * 2, stream);   // HST + CST
    for (int c = 0; c < 5; c++) {
      int t0 = c * 10;
      if (l == 0) {
        hipLaunchKernelGGL(k_noiseconv, dim3(8192), dim3(256), 0, stream, noise, NCH, t0);
        gemm(true, NCH, 448, WIH0, 448, BSUM, GGB, t0, nullptr, 0, IHC, 1024, 20480, 1024, 448, 0);
      } else {
        const ushort* Aip = HBUF + (size_t)t0 * 2048 * 256;
        gemm(true, Aip, 256, (l == 1 ? WIH1 : WIH2), 256, BSUM + l * 1024, nullptr, 0,
             nullptr, 0, IHC, 1024, 20480, 1024, 256, 0);
      }
      hipLaunchKernelGGL(k_rec, dim3(128), dim3(512), 0, stream,
                         IHC, (l == 0 ? WHH0 : l == 1 ? WHH1 : WHH2), HST, CST,
                         (l < 2 ? HBUF : (ushort*)nullptr),
                         (l == 2 ? out_seq : (float*)nullptr), t0);
    }
  }

  // consumer MLP
  hipLaunchKernelGGL(k_cffill, dim3(5256), dim3(256), 0, stream, HST, RECB, CFB);
  gemm(false, CFB, 704, WC1, 704, cb1, nullptr, 0, nullptr, 0, C1B, 512, 2048, 512, 704, 1);
  gemm(false, C1B, 512, WC2, 512, cb2, nullptr, 0, nullptr, 0, C2B, 256, 2048, 256, 512, 1);
  gemm(false, C2B, 256, WC3, 256, cb3, nullptr, 0, C3F, 64, nullptr, 0, 2048, 64, 256, 2);
  hipLaunchKernelGGL(k_cons, dim3(1), dim3(256), 0, stream, C3F, cw4, cb4, out_cons);

  // valence + entropy
  hipLaunchKernelGGL(k_val, dim3(2048), dim3(256), 0, stream, out_seq, out_val);
  hipLaunchKernelGGL(k_ent, dim3(32), dim3(64), 0, stream, AMPR, AMPI, ENTP);
  hipLaunchKernelGGL(k_entfin, dim3(1), dim3(32), 0, stream, ENTP, out_ent);
}